// Round 19
// baseline (406.647 us; speedup 1.0000x reference)
//
#include <hip/hip_runtime.h>
#include <hip/hip_fp16.h>

#define LB __launch_bounds__(256)

typedef unsigned short u16;
typedef unsigned int   u32;
typedef __attribute__((ext_vector_type(8))) short bf16x8;   // 8 bf16 (4 VGPRs)
typedef __attribute__((ext_vector_type(4))) float f32x4;
typedef __attribute__((ext_vector_type(8))) u16  u16x8;

__device__ __forceinline__ u16 f2b(float f) {
    u32 u = __float_as_uint(f);
    u32 r = (u + 0x7fffu + ((u >> 16) & 1u)) >> 16;
    return (u16)r;
}
__device__ __forceinline__ float b2f(u16 h) {
    return __uint_as_float((u32)h << 16);
}

#define QSCALE 0.17677669529663687f

// ---------------------------------------------------------------------------
// B=2 N=256 C=256 HF=WF=64 ROI=15(225) HID=256 HEADS=8 Dh=32 DEPTH=3 FFN=1024
// NQ=16 -> seqs S=512, MT=8192.
// r19: self-attn v3 fuses the QKV projection in-wave (A-frags of tgt loaded
// once, 6x 8-MFMA chains -> Q'/K' row-major + V'^T; deletes selfQKV GEMM and
// the Sb16 round-trip). KVb3 GEMM rebalanced to BM=64 (3 blocks/CU).
// Cross-attn v3 (fused Q-proj) r18-verified.
// ---------------------------------------------------------------------------

// ---------- weights fp32 -> bf16 arena + repack + (tail blocks) prep -------
__global__ LB void k_wconv(const float* __restrict__ s0, const float* __restrict__ s1,
                           const float* __restrict__ s2, const float* __restrict__ s3,
                           const float* __restrict__ s4, const float* __restrict__ s5,
                           const float* __restrict__ s6, u16* __restrict__ dst,
                           const unsigned char* __restrict__ m, int* __restrict__ valid,
                           const float* __restrict__ pb,
                           const float* __restrict__ cqkv_b,
                           float* __restrict__ ckv)
{
    if (blockIdx.x >= 14336) {
        const int pblk = blockIdx.x - 14336;
        if (pblk == 0) {
            __shared__ int flag;
            if (threadIdx.x == 0) flag = 0;
            __syncthreads();
            int loc = 0;
            for (int off = threadIdx.x; off < 512; off += 256)
                if ((off & 3) != 0 && m[off] != 0) loc = 1;
            if (loc) atomicOr(&flag, 1);
            __syncthreads();
            const bool bytelay = (flag != 0);
            for (int s = threadIdx.x; s < 512; s += 256)
                valid[s] = bytelay ? (int)(m[s] != 0) : (int)(((const int*)m)[s] != 0);
        } else {
            const int l = pblk - 1;   // 0..2
            const float* Wv = s3 + (size_t)l * 196608 + 131072;
            const float* vb = cqkv_b + (size_t)l * 768 + 512;
            const int o = threadIdx.x;
            float c = 0.f;
            for (int cc = 0; cc < 256; cc += 4) {
                const float4 p4 = *(const float4*)(pb + cc);
                const float4 v4 = *(const float4*)(Wv + (size_t)o * 256 + cc);
                c += p4.x * v4.x + p4.y * v4.y + p4.z * v4.z + p4.w * v4.w;
            }
            ckv[l * 512 + o]       = cqkv_b[(size_t)l * 768 + o];  // bq (fused Q-proj)
            ckv[l * 512 + 256 + o] = c + vb[o];                    // cv (epilogue)
        }
        return;
    }
    const int e = blockIdx.x * 256 + threadIdx.x;
    if (e >= 3670016) return;
    float v;
    int i = e;
    if (i < 65536) v = s0[i];
    else if ((i -= 65536) < 589824) v = s1[i];
    else if ((i -= 589824) < 196608) v = s2[i];
    else if ((i -= 196608) < 589824) v = s3[i];
    else if ((i -= 589824) < 196608) v = s4[i];
    else if ((i -= 196608) < 786432) v = s5[i];
    else if ((i -= 786432) < 786432) v = s6[i];
    else if ((i -= 786432) < 393216) {  // wCKV3: [l][512 rows (Wk|Wv)][256]
        const int l = i / 131072;
        const int r = (i - l * 131072) >> 8;
        const int c = i & 255;
        v = s3[(size_t)l * 196608 + (size_t)(256 + r) * 256 + c];
    } else {                            // projT: [c][o] = proj_w[o][c]
        i -= 393216;
        v = s0[(i & 255) * 256 + (i >> 8)];
    }
    dst[e] = f2b(v);
}

// ---------- transpose image (B,C,64,64) -> (B,4096,C) bf16 -----------------
__global__ LB void k_transpose(const float* __restrict__ img, u16* __restrict__ imgTb)
{
    __shared__ float tile[64][65];
    const int b  = blockIdx.z;
    const int c0 = blockIdx.y * 64;
    const int p0 = blockIdx.x * 64;
    const int t  = threadIdx.x;
    const int tr = t >> 6, tc = t & 63;
#pragma unroll
    for (int p = 0; p < 16; ++p) {
        const int i = p * 4 + tr;
        tile[i][tc] = img[((size_t)(b * 256 + c0 + i)) * 4096 + p0 + tc];
    }
    __syncthreads();
#pragma unroll
    for (int p = 0; p < 16; ++p) {
        const int jj = p * 4 + tr;
        imgTb[((size_t)(b * 4096 + p0 + jj)) * 256 + c0 + tc] = f2b(tile[tc][jj]);
    }
}

// ---------- bf16 MFMA GEMM: C[M,N] = A[M,K](bf16) @ W[N,K](bf16)^T + bias --
template<int BM>
__global__ LB void gemm_mfma(const u16* __restrict__ A, const u16* __restrict__ W,
                             const float* __restrict__ bias,
                             float* __restrict__ Cf, u16* __restrict__ Cb,
                             int M, int N, int K, int relu)
{
    constexpr int BN = 128;
    __shared__ u16 lds[2][(BM + BN) * 64];
    const int t = threadIdx.x;
    const int wid = t >> 6, lane = t & 63;
    const int bm = blockIdx.y * BM, bn = blockIdx.x * BN;
    const int KT = K >> 6;

    auto stage = [&](int buf, int kt) {
        const int k0 = kt * 64;
        const int rr = t >> 3;
        const int u  = t & 7;
#pragma unroll
        for (int q = 0; q < BM / 32; ++q) {
            const int r = q * 32 + rr;
            const u16* src = A + (size_t)(bm + r) * K + k0 + ((u ^ (r & 7)) << 3);
            __builtin_amdgcn_global_load_lds(
                (const __attribute__((address_space(1))) void*)src,
                (__attribute__((address_space(3))) void*)&lds[buf][q * 2048 + wid * 512],
                16, 0, 0);
        }
#pragma unroll
        for (int q = 0; q < 4; ++q) {
            const int r = q * 32 + rr;
            const u16* src = W + (size_t)(bn + r) * K + k0 + ((u ^ (r & 7)) << 3);
            __builtin_amdgcn_global_load_lds(
                (const __attribute__((address_space(1))) void*)src,
                (__attribute__((address_space(3))) void*)&lds[buf][BM * 64 + q * 2048 + wid * 512],
                16, 0, 0);
        }
    };

    const int wr = wid >> 1, wc = wid & 1;
    constexpr int MR = BM / 32;
    f32x4 acc[MR][4];
    const f32x4 z = {0.f, 0.f, 0.f, 0.f};
#pragma unroll
    for (int mi = 0; mi < MR; ++mi)
#pragma unroll
        for (int ni = 0; ni < 4; ++ni) acc[mi][ni] = z;

    const int r16 = lane & 15, kg = lane >> 4;

    stage(0, 0);
    int cur = 0;
    for (int kt = 0; kt < KT; ++kt) {
        asm volatile("s_waitcnt vmcnt(0)" ::: "memory");
        __syncthreads();
        if (kt + 1 < KT) stage(cur ^ 1, kt + 1);
        const u16* pA = lds[cur];
        const u16* pB = lds[cur] + BM * 64;
#pragma unroll
        for (int kk = 0; kk < 2; ++kk) {
            const int s = kk * 4 + kg;
            bf16x8 afr[MR], bfr[4];
#pragma unroll
            for (int mi = 0; mi < MR; ++mi) {
                const int r = wr * (BM / 2) + mi * 16 + r16;
                afr[mi] = *(const bf16x8*)(pA + r * 64 + ((s ^ (r & 7)) << 3));
            }
#pragma unroll
            for (int ni = 0; ni < 4; ++ni) {
                const int c = wc * 64 + ni * 16 + r16;
                bfr[ni] = *(const bf16x8*)(pB + c * 64 + ((s ^ (c & 7)) << 3));
            }
#pragma unroll
            for (int mi = 0; mi < MR; ++mi)
#pragma unroll
                for (int ni = 0; ni < 4; ++ni)
                    acc[mi][ni] = __builtin_amdgcn_mfma_f32_16x16x32_bf16(
                        afr[mi], bfr[ni], acc[mi][ni], 0, 0, 0);
        }
        cur ^= 1;
    }

#pragma unroll
    for (int mi = 0; mi < MR; ++mi) {
#pragma unroll
        for (int ni = 0; ni < 4; ++ni) {
            const int col = bn + wc * 64 + ni * 16 + r16;
            const float bs = bias ? bias[col] : 0.0f;
#pragma unroll
            for (int rg = 0; rg < 4; ++rg) {
                const int row = bm + wr * (BM / 2) + mi * 16 + kg * 4 + rg;
                float v = acc[mi][ni][rg] + bs;
                if (relu) v = fmaxf(v, 0.0f);
                if (Cf) Cf[(size_t)row * N + col] = v;
                if (Cb) Cb[(size_t)row * N + col] = f2b(v);
            }
        }
    }
}

// ---------- fused GEMM + residual + LayerNorm (+ optional output head) -----
__global__ LB void gemm_ln(const u16* __restrict__ A, const u16* __restrict__ W,
                           const float* __restrict__ bias,
                           float* __restrict__ tgt, u16* __restrict__ tgtb,
                           const float* __restrict__ lnw, const float* __restrict__ lnb,
                           int K,
                           const float* __restrict__ ow, const float* __restrict__ ob,
                           float* __restrict__ outp)
{
    __shared__ u16 lA[32 * 64];
    __shared__ u16 lB[256 * 64];
    __shared__ float psum[2][32];
    __shared__ float psq[2][32];
    __shared__ float hsum[2][32][4];
    const int t = threadIdx.x;
    const int wid = t >> 6, lane = t & 63;
    const int r16 = lane & 15, kg = lane >> 4;
    const int wr = wid >> 1, wc = wid & 1;
    const int bm = blockIdx.x * 32;
    const int KT = K >> 6;

    f32x4 acc[8];
    const f32x4 z = {0.f, 0.f, 0.f, 0.f};
#pragma unroll
    for (int ni = 0; ni < 8; ++ni) acc[ni] = z;

    for (int kt = 0; kt < KT; ++kt) {
        const int k0 = kt * 64;
        const int rr = t >> 3;
        const int u  = t & 7;
        {
            const int r = rr;
            const u16* src = A + (size_t)(bm + r) * K + k0 + ((u ^ (r & 7)) << 3);
            __builtin_amdgcn_global_load_lds(
                (const __attribute__((address_space(1))) void*)src,
                (__attribute__((address_space(3))) void*)&lA[wid * 512],
                16, 0, 0);
        }
#pragma unroll
        for (int q = 0; q < 8; ++q) {
            const int r = q * 32 + rr;
            const u16* src = W + (size_t)r * K + k0 + ((u ^ (r & 7)) << 3);
            __builtin_amdgcn_global_load_lds(
                (const __attribute__((address_space(1))) void*)src,
                (__attribute__((address_space(3))) void*)&lB[q * 2048 + wid * 512],
                16, 0, 0);
        }
        asm volatile("s_waitcnt vmcnt(0)" ::: "memory");
        __syncthreads();
#pragma unroll
        for (int kk = 0; kk < 2; ++kk) {
            const int s = kk * 4 + kg;
            const int ra = wr * 16 + r16;
            const bf16x8 afr = *(const bf16x8*)(lA + ra * 64 + ((s ^ (ra & 7)) << 3));
#pragma unroll
            for (int ni = 0; ni < 8; ++ni) {
                const int c = wc * 128 + ni * 16 + r16;
                const bf16x8 bfr = *(const bf16x8*)(lB + c * 64 + ((s ^ (c & 7)) << 3));
                acc[ni] = __builtin_amdgcn_mfma_f32_16x16x32_bf16(afr, bfr, acc[ni], 0, 0, 0);
            }
        }
        __syncthreads();
    }

    float xv[4][8];
    float bcol[8], wcol[8], bncol[8];
#pragma unroll
    for (int ni = 0; ni < 8; ++ni) {
        const int c = wc * 128 + ni * 16 + r16;
        bcol[ni]  = bias[c];
        wcol[ni]  = lnw[c];
        bncol[ni] = lnb[c];
    }
#pragma unroll
    for (int rg = 0; rg < 4; ++rg) {
        const int row = bm + wr * 16 + kg * 4 + rg;
#pragma unroll
        for (int ni = 0; ni < 8; ++ni) {
            const int c = wc * 128 + ni * 16 + r16;
            xv[rg][ni] = tgt[(size_t)row * 256 + c] + acc[ni][rg] + bcol[ni];
        }
    }
#pragma unroll
    for (int rg = 0; rg < 4; ++rg) {
        float s = 0.f;
#pragma unroll
        for (int ni = 0; ni < 8; ++ni) s += xv[rg][ni];
#pragma unroll
        for (int m = 1; m < 16; m <<= 1) s += __shfl_xor(s, m);
        if (r16 == 0) psum[wc][wr * 16 + kg * 4 + rg] = s;
    }
    __syncthreads();
    float mu[4];
#pragma unroll
    for (int rg = 0; rg < 4; ++rg) {
        const int rl = wr * 16 + kg * 4 + rg;
        mu[rg] = (psum[0][rl] + psum[1][rl]) * (1.0f / 256.0f);
    }
#pragma unroll
    for (int rg = 0; rg < 4; ++rg) {
        float q = 0.f;
#pragma unroll
        for (int ni = 0; ni < 8; ++ni) {
            const float d = xv[rg][ni] - mu[rg];
            q += d * d;
        }
#pragma unroll
        for (int m = 1; m < 16; m <<= 1) q += __shfl_xor(q, m);
        if (r16 == 0) psq[wc][wr * 16 + kg * 4 + rg] = q;
    }
    __syncthreads();
    float onorm[4][8];
#pragma unroll
    for (int rg = 0; rg < 4; ++rg) {
        const int rl = wr * 16 + kg * 4 + rg;
        const int row = bm + rl;
        const float var = (psq[0][rl] + psq[1][rl]) * (1.0f / 256.0f);
        const float inv = 1.0f / sqrtf(var + 1e-5f);
#pragma unroll
        for (int ni = 0; ni < 8; ++ni) {
            const int c = wc * 128 + ni * 16 + r16;
            const float o = (xv[rg][ni] - mu[rg]) * inv * wcol[ni] + bncol[ni];
            onorm[rg][ni] = o;
            tgt[(size_t)row * 256 + c]  = o;
            tgtb[(size_t)row * 256 + c] = f2b(o);
        }
    }

    if (outp) {
#pragma unroll
        for (int j = 0; j < 4; ++j) {
            float wj[8];
#pragma unroll
            for (int ni = 0; ni < 8; ++ni)
                wj[ni] = ow[j * 256 + wc * 128 + ni * 16 + r16];
#pragma unroll
            for (int rg = 0; rg < 4; ++rg) {
                float p = 0.f;
#pragma unroll
                for (int ni = 0; ni < 8; ++ni) p += onorm[rg][ni] * wj[ni];
#pragma unroll
                for (int m = 1; m < 16; m <<= 1) p += __shfl_xor(p, m);
                if (r16 == 0) hsum[wc][wr * 16 + kg * 4 + rg][j] = p;
            }
        }
        __syncthreads();
        if (t < 128) {
            const int row = t >> 2, j = t & 3;
            outp[(size_t)(bm + row) * 4 + j] =
                hsum[0][row][j] + hsum[1][row][j] + ob[j];
        }
    }
}

// ---------- init tgt (fp32 + bf16) -----------------------------------------
__global__ LB void k_init_tgt(float* __restrict__ tgt, u16* __restrict__ tgtb,
                              const float* __restrict__ qe)
{
    const int e = blockIdx.x * 256 + threadIdx.x;
    const int c = e & 255;
    const int row = e >> 8;
    const int i = row & 15;
    const float v = qe[(i << 8) | c];
    tgt[e] = v;
    tgtb[e] = f2b(v);
}

// ---------- self attention v3: fused QKV-proj + wave-per-head chain --------
// tgtb bf16 [8192][256]; wQKV [768][256] (layer); bqkv [768] (layer).
__global__ LB void k_self_attn(const u16* __restrict__ tgtb,
                               const u16* __restrict__ wQKV,
                               const float* __restrict__ bqkv,
                               u16* __restrict__ O)
{
    __shared__ __align__(16) u16 arena[4][2560];
    const int t = threadIdx.x;
    const int lane = t & 63, wid = t >> 6;
    const int r16 = lane & 15, kg = lane >> 4;
    const int blk = blockIdx.x;
    const int s = blk >> 1;
    const int h = (blk & 1) * 4 + wid;

    u16* q_lds = &arena[wid][0];      // [16 q][32 ch]
    u16* k_lds = &arena[wid][512];    // [16 key][32 ch]
    u16* vT    = &arena[wid][1024];   // [32 ch][32 key] (keys 16-31 zero)
    u16* p_lds = &arena[wid][2048];   // [16 q][32 key]  (keys 16-31 zero)

    // preload shared A-fragments (tgt rows of this seq) once
    bf16x8 ta[8];
#pragma unroll
    for (int ks = 0; ks < 8; ++ks)
        ta[ks] = *(const bf16x8*)(tgtb + (size_t)(s * 16 + r16) * 256 + ks * 32 + kg * 8);

    // fused projections: Q'/K' row-major, V' transposed (D-layout stores)
#pragma unroll
    for (int oi = 0; oi < 3; ++oi) {
#pragma unroll
        for (int ct = 0; ct < 2; ++ct) {
            f32x4 acc = {0.f, 0.f, 0.f, 0.f};
#pragma unroll
            for (int ks = 0; ks < 8; ++ks) {
                const bf16x8 wb = *(const bf16x8*)(wQKV +
                    (size_t)(oi * 256 + h * 32 + ct * 16 + r16) * 256 + ks * 32 + kg * 8);
                acc = __builtin_amdgcn_mfma_f32_16x16x32_bf16(ta[ks], wb, acc, 0, 0, 0);
            }
            const float bb = bqkv[oi * 256 + h * 32 + ct * 16 + r16];
#pragma unroll
            for (int rg = 0; rg < 4; ++rg) {
                const int row = kg * 4 + rg;         // q or key index
                const int ch  = ct * 16 + r16;
                const u16 val = f2b(acc[rg] + bb);
                if (oi == 0)      q_lds[row * 32 + ch] = val;
                else if (oi == 1) k_lds[row * 32 + ch] = val;
                else              vT[ch * 32 + row]    = val;
            }
        }
    }
    // zero vT key cols 16-31 and p pad cols 16-31
    {
        const int zc0 = lane >> 1, zk0 = 16 + (lane & 1) * 8;
#pragma unroll
        for (int j = 0; j < 8; ++j) vT[zc0 * 32 + zk0 + j] = 0;
        const int zq = lane & 15, zc = 16 + (lane >> 4) * 4;
#pragma unroll
        for (int j = 0; j < 4; ++j) p_lds[zq * 32 + zc + j] = 0;
    }

    // S = Q' @ K'^T (1 MFMA, full k=32)
    const bf16x8 qfr = *(const bf16x8*)(q_lds + r16 * 32 + kg * 8);
    const bf16x8 kfr = *(const bf16x8*)(k_lds + r16 * 32 + kg * 8);
    f32x4 sv = {0.f, 0.f, 0.f, 0.f};
    sv = __builtin_amdgcn_mfma_f32_16x16x32_bf16(qfr, kfr, sv, 0, 0, 0);

    float ev[4], rowsum[4];
#pragma unroll
    for (int rg = 0; rg < 4; ++rg) ev[rg] = sv[rg] * QSCALE;
#pragma unroll
    for (int rg = 0; rg < 4; ++rg) {
        float mx = ev[rg];
#pragma unroll
        for (int m = 1; m < 16; m <<= 1) mx = fmaxf(mx, __shfl_xor(mx, m));
        ev[rg] = __expf(ev[rg] - mx);
        float ps = ev[rg];
#pragma unroll
        for (int m = 1; m < 16; m <<= 1) ps += __shfl_xor(ps, m);
        rowsum[rg] = ps;
    }

#pragma unroll
    for (int rg = 0; rg < 4; ++rg)
        p_lds[(kg * 4 + rg) * 32 + r16] = f2b(ev[rg]);

    // O = P @ V'^T : 2 MFMA; /rowsum; write
#pragma unroll
    for (int ct = 0; ct < 2; ++ct) {
        const bf16x8 pa = *(const bf16x8*)(p_lds + r16 * 32 + kg * 8);
        const bf16x8 vb = *(const bf16x8*)(vT + (ct * 16 + r16) * 32 + kg * 8);
        f32x4 ao = {0.f, 0.f, 0.f, 0.f};
        ao = __builtin_amdgcn_mfma_f32_16x16x32_bf16(pa, vb, ao, 0, 0, 0);
#pragma unroll
        for (int rg = 0; rg < 4; ++rg) {
            const int q = kg * 4 + rg;
            O[(size_t)(s * 16 + q) * 256 + h * 32 + ct * 16 + r16] = f2b(ao[rg] / rowsum[rg]);
        }
    }
}

// ---------- cross attention v3: fused Q-proj + wave-per-head chain (r18) ---
__global__ LB void k_cross_attn(const u16* __restrict__ tgtb,
                                const u16* __restrict__ wQ,
                                const u16* __restrict__ KV, int kvs,
                                const float* __restrict__ ckv,
                                const int* __restrict__ valid,
                                const float* __restrict__ kps,
                                u16* __restrict__ O)
{
    __shared__ __align__(16) char arena[64832];
    u16* Wm  = (u16*)arena;
    u16* WmT = (u16*)(arena + 14400);

    const int t = threadIdx.x;
    const int lane = t & 63, wid = t >> 6;
    const int r16 = lane & 15, kg = lane >> 4;
    const int blk = blockIdx.x;
    const int s = blk >> 1;
    const int h = (blk & 1) * 4 + wid;
    const int b = s >> 8, n = s & 255;

    u16* buf = (u16*)(arena + 22848 + wid * 10496);
    u16* p_b = (u16*)(arena + 22848 + wid * 10496 + 2048);
    u16* QP  = p_b;

    for (int e = t; e < 16208; e += 256) ((u32*)arena)[e] = 0;
    __syncthreads();

    const float kpy = kps[(b * 256 + n) * 2 + 0];
    const float kpx = kps[(b * 256 + n) * 2 + 1];
    const float gx0 = rintf(kpx) - 7.0f;
    const float gy0 = rintf(kpy) - 7.0f;
    const float gxn0 = gx0 / 511.0f * 2.0f - 1.0f;
    const float gyn0 = gy0 / 511.0f * 2.0f - 1.0f;
    const float xb = ((gxn0 + 1.f) * 64.f - 1.f) * 0.5f;
    const float yb = ((gyn0 + 1.f) * 64.f - 1.f) * 0.5f;
    const int x0b = (int)floorf(xb);
    const int y0b = (int)floorf(yb);

    if (t < 225) {
        const int iy = t / 15, ix = t - iy * 15;
        const float gy = rintf(kpy) + (float)(iy - 7);
        const float gx = rintf(kpx) + (float)(ix - 7);
        const float gxn = gx / 511.0f * 2.0f - 1.0f;
        const float gyn = gy / 511.0f * 2.0f - 1.0f;
        const bool inval = (gxn < -1.f) || (gyn < -1.f) || (gxn > 1.f) || (gyn > 1.f);
        const float x = ((gxn + 1.f) * 64.f - 1.f) * 0.5f;
        const float y = ((gyn + 1.f) * 64.f - 1.f) * 0.5f;
        const float x0f = floorf(x), y0f = floorf(y);
        const float wx = x - x0f, wy = y - y0f;
        const int x0 = (int)x0f, y0 = (int)y0f;
#pragma unroll
        for (int tt = 0; tt < 4; ++tt) {
            const int dy = tt >> 1, dx = tt & 1;
            const int yi = y0 + dy, xi = x0 + dx;
            const bool ok = (yi >= 0) && (yi < 64) && (xi >= 0) && (xi < 64) && !inval;
            const float w = (dy ? wy : 1.f - wy) * (dx ? wx : 1.f - wx);
            if (ok) {
                const int cell = (yi - y0b) * 4 + (xi - x0b);
                const u16 wb = f2b(w);
                Wm[t * 32 + ((((cell >> 3) ^ (t & 3)) << 3) | (cell & 7))] = wb;
                WmT[cell * 264 + t] = wb;
            }
        }
    }
#pragma unroll
    for (int ct = 0; ct < 2; ++ct) {
        f32x4 aq = {0.f, 0.f, 0.f, 0.f};
#pragma unroll
        for (int ks = 0; ks < 8; ++ks) {
            const bf16x8 ta = *(const bf16x8*)(tgtb + (size_t)(s * 16 + r16) * 256 + ks * 32 + kg * 8);
            const bf16x8 wb = *(const bf16x8*)(wQ + (size_t)(h * 32 + ct * 16 + r16) * 256 + ks * 32 + kg * 8);
            aq = __builtin_amdgcn_mfma_f32_16x16x32_bf16(ta, wb, aq, 0, 0, 0);
        }
        const float bq = ckv[h * 32 + ct * 16 + r16];
#pragma unroll
        for (int rg = 0; rg < 4; ++rg)
            QP[(kg * 4 + rg) * 40 + ct * 16 + r16] = f2b(aq[rg] + bq);
    }
    const int cell = lane >> 2, ch8 = (lane & 3) * 8;
    const int cy = cell >> 2, cx = cell & 3;
    const int py = min(max(y0b + cy, 0), 63);
    const int px = min(max(x0b + cx, 0), 63);
    const size_t texidx = (size_t)(b * 4096 + py * 64 + px) * kvs + h * 32 + ch8;
    *(u16x8*)(buf + cell * 32 + ch8) = *(const u16x8*)(KV + texidx);
    const bool vld = valid[s] != 0;
    __syncthreads();

    {
        const bf16x8 qfr = *(const bf16x8*)(QP + r16 * 40 + kg * 8);
        const bf16x8 tfr = *(const bf16x8*)(buf + r16 * 32 + kg * 8);
        f32x4 aq = {0.f, 0.f, 0.f, 0.f};
        aq = __builtin_amdgcn_mfma_f32_16x16x32_bf16(qfr, tfr, aq, 0, 0, 0);
#pragma unroll
        for (int rg = 0; rg < 4; ++rg)
            QP[(kg * 4 + rg) * 40 + r16] = f2b(aq[rg]);
    }

    float ev[4][15];
    {
        const bf16x8 afr = *(const bf16x8*)(QP + r16 * 40 + kg * 8);
#pragma unroll
        for (int tile = 0; tile < 15; ++tile) {
            const int p = tile * 16 + r16;
            const int rc = p < 225 ? p : 224;
            const bf16x8 bfr = *(const bf16x8*)(Wm + rc * 32 + ((kg ^ (rc & 3)) << 3));
            f32x4 acc = {0.f, 0.f, 0.f, 0.f};
            acc = __builtin_amdgcn_mfma_f32_16x16x32_bf16(afr, bfr, acc, 0, 0, 0);
#pragma unroll
            for (int rg = 0; rg < 4; ++rg) {
                float sv = acc[rg] * QSCALE;
                if (p > 224) sv = -1e30f;
                if (!vld && p > 0) sv = -1e30f;
                ev[rg][tile] = sv;
            }
        }
    }
    float rowsumv[4];
#pragma unroll
    for (int rg = 0; rg < 4; ++rg) {
        float mx = -1e30f;
#pragma unroll
        for (int k = 0; k < 15; ++k) mx = fmaxf(mx, ev[rg][k]);
#pragma unroll
        for (int m = 1; m < 16; m <<= 1) mx = fmaxf(mx, __shfl_xor(mx, m));
        float ps = 0.f;
#pragma unroll
        for (int k = 0; k < 15; ++k) {
            ev[rg][k] = __expf(ev[rg][k] - mx);
            ps += ev[rg][k];
        }
#pragma unroll
        for (int m = 1; m < 16; m <<= 1) ps += __shfl_xor(ps, m);
        rowsumv[rg] = ps;
    }

#pragma unroll
    for (int rg = 0; rg < 4; ++rg)
#pragma unroll
        for (int k = 0; k < 15; ++k) {
            const int p = k * 16 + r16;
            if (p < 225) p_b[(kg * 4 + rg) * 264 + p] = f2b(ev[rg][k]);
        }
    for (int e = lane; e < 496; e += 64) {
        const int row = e / 31;
        p_b[row * 264 + 225 + (e - row * 31)] = 0;
    }

    {
        const u16x8 v = *(const u16x8*)(KV + texidx + 256);
#pragma unroll
        for (int j = 0; j < 8; ++j)
            buf[(ch8 + j) * 32 + cell] = ((const u16*)&v)[j];
        const int zr = lane & 15, zc0 = 16 + (lane >> 4) * 4;
#pragma unroll
        for (int j = 0; j < 4; ++j) buf[zr * 32 + zc0 + j] = 0;
    }

    f32x4 pw = {0.f, 0.f, 0.f, 0.f};
#pragma unroll
    for (int ks = 0; ks < 8; ++ks) {
        const bf16x8 pa = *(const bf16x8*)(p_b + r16 * 264 + ks * 32 + kg * 8);
        const bf16x8 wb = *(const bf16x8*)(WmT + r16 * 264 + ks * 32 + kg * 8);
        pw = __builtin_amdgcn_mfma_f32_16x16x32_bf16(pa, wb, pw, 0, 0, 0);
    }

#pragma unroll
    for (int rg = 0; rg < 4; ++rg)
        QP[(kg * 4 + rg) * 40 + r16] = f2b(pw[rg]);
    {
        const int zq = lane & 15, zc0 = 16 + (lane >> 4) * 4;
#pragma unroll
        for (int j = 0; j < 4; ++j) QP[zq * 40 + zc0 + j] = 0;
    }

#pragma unroll
    for (int ct = 0; ct < 2; ++ct) {
        const bf16x8 pa = *(const bf16x8*)(QP + r16 * 40 + kg * 8);
        const bf16x8 vb = *(const bf16x8*)(buf + (ct * 16 + r16) * 32 + kg * 8);
        f32x4 ao = {0.f, 0.f, 0.f, 0.f};
        ao = __builtin_amdgcn_mfma_f32_16x16x32_bf16(pa, vb, ao, 0, 0, 0);
#pragma unroll
        for (int rg = 0; rg < 4; ++rg) {
            const int q = kg * 4 + rg;
            const int ch = h * 32 + ct * 16 + r16;
            const float val = ao[rg] / rowsumv[rg] + ckv[256 + ch];
            O[(size_t)(s * 16 + q) * 256 + ch] = f2b(val);
        }
    }
}

// ---------------------------------------------------------------------------
extern "C" void kernel_launch(void* const* d_in, const int* in_sizes, int n_in,
                              void* d_out, int out_size, void* d_ws, size_t ws_size,
                              hipStream_t stream)
{
    const float* img          = (const float*)d_in[0];
    const float* kps          = (const float*)d_in[1];
    const unsigned char* vmsk = (const unsigned char*)d_in[2];
    const float* proj_w       = (const float*)d_in[3];
    const float* proj_b       = (const float*)d_in[4];
    const float* query_embed  = (const float*)d_in[5];
    const float* self_qkv_w   = (const float*)d_in[6];
    const float* self_qkv_b   = (const float*)d_in[7];
    const float* self_out_w   = (const float*)d_in[8];
    const float* self_out_b   = (const float*)d_in[9];
    const float* cross_qkv_w  = (const float*)d_in[10];
    const float* cross_qkv_b  = (const float*)d_in[11];
    const float* cross_out_w  = (const float*)d_in[12];
    const float* cross_out_b  = (const float*)d_in[13];
    const float* ffn1_w       = (const float*)d_in[14];
    const float* ffn1_b       = (const float*)d_in[15];
    const float* ffn2_w       = (const float*)d_in[16];
    const float* ffn2_b       = (const float*)d_in[17];
    const float* ln1_w        = (const float*)d_in[18];
    const float* ln1_b        = (const float*)d_in[19];
    const float* ln2_w        = (const float*)d_in[20];
    const float* ln2_b        = (const float*)d_in[21];
    const float* ln3_w        = (const float*)d_in[22];
    const float* ln3_b        = (const float*)d_in[23];
    const float* out_w        = (const float*)d_in[24];
    const float* out_b        = (const float*)d_in[25];
    float* out = (float*)d_out;

    // ---- workspace layout (~68 MB) ----
    char* W8 = (char*)d_ws;
    size_t off = 0;
    auto alloc = [&](size_t bytes) { void* p = W8 + off; off += (bytes + 255) & ~(size_t)255; return p; };
    float* tgt   = (float*)alloc(2097152 * 4);
    float* ckv   = (float*)alloc(3 * 512 * 4);
    u16* imgTb   = (u16*)alloc(2097152 * 2);
    u16* KVb3    = (u16*)alloc(12582912 * 2);    // [8192][1536] all 3 layers K|V
    u16* tgtb    = (u16*)alloc(2097152 * 2);
    u16* Abuf    = (u16*)alloc(2097152 * 2);
    u16* Hbuf    = (u16*)alloc(8388608 * 2);
    u16* wAll    = (u16*)alloc(3670016 * 2);
    u16* WcombB  = (u16*)alloc(393216 * 2);      // (wCKV3 @ proj) weights
    int* valid   = (int*)alloc(512 * 4);

    u16* wProj  = wAll;             // 65536 (layout keeper)
    u16* wSQKV  = wProj + 65536;    // 3*768*256
    u16* wSOut  = wSQKV + 589824;   // 3*256*256
    u16* wCQKV  = wSOut + 196608;   // 3*768*256 (rows 0-255 of each layer = Wq)
    u16* wCOut  = wCQKV + 589824;   // 3*256*256
    u16* wF1    = wCOut + 196608;   // 3*1024*256
    u16* wF2    = wF1 + 786432;     // 3*256*1024
    u16* wCKV3  = wF2 + 786432;     // 3*512*256 cross K|V weights
    u16* wProjT = wCKV3 + 393216;   // 256*256 proj^T

    k_wconv<<<14340, 256, 0, stream>>>(proj_w, self_qkv_w, self_out_w, cross_qkv_w,
                                       cross_out_w, ffn1_w, ffn2_w, wAll,
                                       vmsk, valid, proj_b, cross_qkv_b, ckv);
    k_transpose<<<dim3(64, 4, 2), 256, 0, stream>>>(img, imgTb);
    gemm_mfma<64><<<dim3(2, 24), 256, 0, stream>>>(wCKV3, wProjT, nullptr,
                                                   nullptr, WcombB, 1536, 256, 256, 0);
    gemm_mfma<64><<<dim3(12, 128), 256, 0, stream>>>(imgTb, WcombB, nullptr,
                                                     nullptr, KVb3, 8192, 1536, 256, 0);
    k_init_tgt<<<8192, 256, 0, stream>>>(tgt, tgtb, query_embed);

    for (int l = 0; l < 3; ++l) {
        const int last = (l == 2);
        // ---- self attention (QKV-proj fused in-wave) ----
        k_self_attn<<<1024, 256, 0, stream>>>(tgtb, wSQKV + (size_t)l * 196608,
                                              self_qkv_b + (size_t)l * 768, Abuf);
        gemm_ln<<<256, 256, 0, stream>>>(Abuf, wSOut + (size_t)l * 65536,
            self_out_b + (size_t)l * 256, tgt, tgtb,
            ln1_w + (size_t)l * 256, ln1_b + (size_t)l * 256, 256,
            nullptr, nullptr, nullptr);

        // ---- cross attention (Q-proj fused in-wave) ----
        k_cross_attn<<<1024, 256, 0, stream>>>(tgtb, wCQKV + (size_t)l * 196608,
                                               KVb3 + (size_t)l * 512, 1536,
                                               ckv + (size_t)l * 512, valid, kps, Abuf);
        gemm_ln<<<256, 256, 0, stream>>>(Abuf, wCOut + (size_t)l * 65536,
            cross_out_b + (size_t)l * 256, tgt, tgtb,
            ln2_w + (size_t)l * 256, ln2_b + (size_t)l * 256, 256,
            nullptr, nullptr, nullptr);

        // ---- FFN (final layer fuses the output head) ----
        gemm_mfma<64><<<dim3(8, 128), 256, 0, stream>>>(tgtb, wF1 + (size_t)l * 262144,
            ffn1_b + (size_t)l * 1024, nullptr, Hbuf, 8192, 1024, 256, 1);
        gemm_ln<<<256, 256, 0, stream>>>(Hbuf, wF2 + (size_t)l * 262144,
            ffn2_b + (size_t)l * 256, tgt, tgtb,
            ln3_w + (size_t)l * 256, ln3_b + (size_t)l * 256, 1024,
            last ? out_w : nullptr, last ? out_b : nullptr, last ? out : nullptr);
    }
}

// Round 20
// 365.333 us; speedup vs baseline: 1.1131x; 1.1131x over previous
//
#include <hip/hip_runtime.h>
#include <hip/hip_fp16.h>

#define LB __launch_bounds__(256)

typedef unsigned short u16;
typedef unsigned int   u32;
typedef __attribute__((ext_vector_type(8))) short bf16x8;   // 8 bf16 (4 VGPRs)
typedef __attribute__((ext_vector_type(4))) float f32x4;
typedef __attribute__((ext_vector_type(8))) u16  u16x8;

__device__ __forceinline__ u16 f2b(float f) {
    u32 u = __float_as_uint(f);
    u32 r = (u + 0x7fffu + ((u >> 16) & 1u)) >> 16;
    return (u16)r;
}
__device__ __forceinline__ float b2f(u16 h) {
    return __uint_as_float((u32)h << 16);
}

#define QSCALE 0.17677669529663687f

// ---------------------------------------------------------------------------
// B=2 N=256 C=256 HF=WF=64 ROI=15(225) HID=256 HEADS=8 Dh=32 DEPTH=3 FFN=1024
// NQ=16 -> seqs S=512, MT=8192.
// r20 = r18 (verified 371us) + KVb3 BM=64 rebalance (the one sound r19 change).
// Self-attn v3 QKV-fusion REVERTED: 1024 blocks streaming per-head wQKV slices
// = ~196MB/layer weight traffic vs GEMM's LDS-amortized reuse (r19 post-mortem).
// Cross-attn keeps fused Q-proj (1/3 weights; replaced a full GEMM round-trip).
// ---------------------------------------------------------------------------

// ---------- weights fp32 -> bf16 arena + repack + (tail blocks) prep -------
__global__ LB void k_wconv(const float* __restrict__ s0, const float* __restrict__ s1,
                           const float* __restrict__ s2, const float* __restrict__ s3,
                           const float* __restrict__ s4, const float* __restrict__ s5,
                           const float* __restrict__ s6, u16* __restrict__ dst,
                           const unsigned char* __restrict__ m, int* __restrict__ valid,
                           const float* __restrict__ pb,
                           const float* __restrict__ cqkv_b,
                           float* __restrict__ ckv)
{
    if (blockIdx.x >= 14336) {
        const int pblk = blockIdx.x - 14336;
        if (pblk == 0) {
            __shared__ int flag;
            if (threadIdx.x == 0) flag = 0;
            __syncthreads();
            int loc = 0;
            for (int off = threadIdx.x; off < 512; off += 256)
                if ((off & 3) != 0 && m[off] != 0) loc = 1;
            if (loc) atomicOr(&flag, 1);
            __syncthreads();
            const bool bytelay = (flag != 0);
            for (int s = threadIdx.x; s < 512; s += 256)
                valid[s] = bytelay ? (int)(m[s] != 0) : (int)(((const int*)m)[s] != 0);
        } else {
            const int l = pblk - 1;   // 0..2
            const float* Wv = s3 + (size_t)l * 196608 + 131072;
            const float* vb = cqkv_b + (size_t)l * 768 + 512;
            const int o = threadIdx.x;
            float c = 0.f;
            for (int cc = 0; cc < 256; cc += 4) {
                const float4 p4 = *(const float4*)(pb + cc);
                const float4 v4 = *(const float4*)(Wv + (size_t)o * 256 + cc);
                c += p4.x * v4.x + p4.y * v4.y + p4.z * v4.z + p4.w * v4.w;
            }
            ckv[l * 512 + o]       = cqkv_b[(size_t)l * 768 + o];  // bq (fused Q-proj)
            ckv[l * 512 + 256 + o] = c + vb[o];                    // cv (epilogue)
        }
        return;
    }
    const int e = blockIdx.x * 256 + threadIdx.x;
    if (e >= 3670016) return;
    float v;
    int i = e;
    if (i < 65536) v = s0[i];
    else if ((i -= 65536) < 589824) v = s1[i];
    else if ((i -= 589824) < 196608) v = s2[i];
    else if ((i -= 196608) < 589824) v = s3[i];
    else if ((i -= 589824) < 196608) v = s4[i];
    else if ((i -= 196608) < 786432) v = s5[i];
    else if ((i -= 786432) < 786432) v = s6[i];
    else if ((i -= 786432) < 393216) {  // wCKV3: [l][512 rows (Wk|Wv)][256]
        const int l = i / 131072;
        const int r = (i - l * 131072) >> 8;
        const int c = i & 255;
        v = s3[(size_t)l * 196608 + (size_t)(256 + r) * 256 + c];
    } else {                            // projT: [c][o] = proj_w[o][c]
        i -= 393216;
        v = s0[(i & 255) * 256 + (i >> 8)];
    }
    dst[e] = f2b(v);
}

// ---------- transpose image (B,C,64,64) -> (B,4096,C) bf16 -----------------
__global__ LB void k_transpose(const float* __restrict__ img, u16* __restrict__ imgTb)
{
    __shared__ float tile[64][65];
    const int b  = blockIdx.z;
    const int c0 = blockIdx.y * 64;
    const int p0 = blockIdx.x * 64;
    const int t  = threadIdx.x;
    const int tr = t >> 6, tc = t & 63;
#pragma unroll
    for (int p = 0; p < 16; ++p) {
        const int i = p * 4 + tr;
        tile[i][tc] = img[((size_t)(b * 256 + c0 + i)) * 4096 + p0 + tc];
    }
    __syncthreads();
#pragma unroll
    for (int p = 0; p < 16; ++p) {
        const int jj = p * 4 + tr;
        imgTb[((size_t)(b * 4096 + p0 + jj)) * 256 + c0 + tc] = f2b(tile[tc][jj]);
    }
}

// ---------- bf16 MFMA GEMM: C[M,N] = A[M,K](bf16) @ W[N,K](bf16)^T + bias --
template<int BM>
__global__ LB void gemm_mfma(const u16* __restrict__ A, const u16* __restrict__ W,
                             const float* __restrict__ bias,
                             float* __restrict__ Cf, u16* __restrict__ Cb,
                             int M, int N, int K, int relu)
{
    constexpr int BN = 128;
    __shared__ u16 lds[2][(BM + BN) * 64];
    const int t = threadIdx.x;
    const int wid = t >> 6, lane = t & 63;
    const int bm = blockIdx.y * BM, bn = blockIdx.x * BN;
    const int KT = K >> 6;

    auto stage = [&](int buf, int kt) {
        const int k0 = kt * 64;
        const int rr = t >> 3;
        const int u  = t & 7;
#pragma unroll
        for (int q = 0; q < BM / 32; ++q) {
            const int r = q * 32 + rr;
            const u16* src = A + (size_t)(bm + r) * K + k0 + ((u ^ (r & 7)) << 3);
            __builtin_amdgcn_global_load_lds(
                (const __attribute__((address_space(1))) void*)src,
                (__attribute__((address_space(3))) void*)&lds[buf][q * 2048 + wid * 512],
                16, 0, 0);
        }
#pragma unroll
        for (int q = 0; q < 4; ++q) {
            const int r = q * 32 + rr;
            const u16* src = W + (size_t)(bn + r) * K + k0 + ((u ^ (r & 7)) << 3);
            __builtin_amdgcn_global_load_lds(
                (const __attribute__((address_space(1))) void*)src,
                (__attribute__((address_space(3))) void*)&lds[buf][BM * 64 + q * 2048 + wid * 512],
                16, 0, 0);
        }
    };

    const int wr = wid >> 1, wc = wid & 1;
    constexpr int MR = BM / 32;
    f32x4 acc[MR][4];
    const f32x4 z = {0.f, 0.f, 0.f, 0.f};
#pragma unroll
    for (int mi = 0; mi < MR; ++mi)
#pragma unroll
        for (int ni = 0; ni < 4; ++ni) acc[mi][ni] = z;

    const int r16 = lane & 15, kg = lane >> 4;

    stage(0, 0);
    int cur = 0;
    for (int kt = 0; kt < KT; ++kt) {
        asm volatile("s_waitcnt vmcnt(0)" ::: "memory");
        __syncthreads();
        if (kt + 1 < KT) stage(cur ^ 1, kt + 1);
        const u16* pA = lds[cur];
        const u16* pB = lds[cur] + BM * 64;
#pragma unroll
        for (int kk = 0; kk < 2; ++kk) {
            const int s = kk * 4 + kg;
            bf16x8 afr[MR], bfr[4];
#pragma unroll
            for (int mi = 0; mi < MR; ++mi) {
                const int r = wr * (BM / 2) + mi * 16 + r16;
                afr[mi] = *(const bf16x8*)(pA + r * 64 + ((s ^ (r & 7)) << 3));
            }
#pragma unroll
            for (int ni = 0; ni < 4; ++ni) {
                const int c = wc * 64 + ni * 16 + r16;
                bfr[ni] = *(const bf16x8*)(pB + c * 64 + ((s ^ (c & 7)) << 3));
            }
#pragma unroll
            for (int mi = 0; mi < MR; ++mi)
#pragma unroll
                for (int ni = 0; ni < 4; ++ni)
                    acc[mi][ni] = __builtin_amdgcn_mfma_f32_16x16x32_bf16(
                        afr[mi], bfr[ni], acc[mi][ni], 0, 0, 0);
        }
        cur ^= 1;
    }

#pragma unroll
    for (int mi = 0; mi < MR; ++mi) {
#pragma unroll
        for (int ni = 0; ni < 4; ++ni) {
            const int col = bn + wc * 64 + ni * 16 + r16;
            const float bs = bias ? bias[col] : 0.0f;
#pragma unroll
            for (int rg = 0; rg < 4; ++rg) {
                const int row = bm + wr * (BM / 2) + mi * 16 + kg * 4 + rg;
                float v = acc[mi][ni][rg] + bs;
                if (relu) v = fmaxf(v, 0.0f);
                if (Cf) Cf[(size_t)row * N + col] = v;
                if (Cb) Cb[(size_t)row * N + col] = f2b(v);
            }
        }
    }
}

// ---------- fused GEMM + residual + LayerNorm (+ optional output head) -----
__global__ LB void gemm_ln(const u16* __restrict__ A, const u16* __restrict__ W,
                           const float* __restrict__ bias,
                           float* __restrict__ tgt, u16* __restrict__ tgtb,
                           const float* __restrict__ lnw, const float* __restrict__ lnb,
                           int K,
                           const float* __restrict__ ow, const float* __restrict__ ob,
                           float* __restrict__ outp)
{
    __shared__ u16 lA[32 * 64];
    __shared__ u16 lB[256 * 64];
    __shared__ float psum[2][32];
    __shared__ float psq[2][32];
    __shared__ float hsum[2][32][4];
    const int t = threadIdx.x;
    const int wid = t >> 6, lane = t & 63;
    const int r16 = lane & 15, kg = lane >> 4;
    const int wr = wid >> 1, wc = wid & 1;
    const int bm = blockIdx.x * 32;
    const int KT = K >> 6;

    f32x4 acc[8];
    const f32x4 z = {0.f, 0.f, 0.f, 0.f};
#pragma unroll
    for (int ni = 0; ni < 8; ++ni) acc[ni] = z;

    for (int kt = 0; kt < KT; ++kt) {
        const int k0 = kt * 64;
        const int rr = t >> 3;
        const int u  = t & 7;
        {
            const int r = rr;
            const u16* src = A + (size_t)(bm + r) * K + k0 + ((u ^ (r & 7)) << 3);
            __builtin_amdgcn_global_load_lds(
                (const __attribute__((address_space(1))) void*)src,
                (__attribute__((address_space(3))) void*)&lA[wid * 512],
                16, 0, 0);
        }
#pragma unroll
        for (int q = 0; q < 8; ++q) {
            const int r = q * 32 + rr;
            const u16* src = W + (size_t)r * K + k0 + ((u ^ (r & 7)) << 3);
            __builtin_amdgcn_global_load_lds(
                (const __attribute__((address_space(1))) void*)src,
                (__attribute__((address_space(3))) void*)&lB[q * 2048 + wid * 512],
                16, 0, 0);
        }
        asm volatile("s_waitcnt vmcnt(0)" ::: "memory");
        __syncthreads();
#pragma unroll
        for (int kk = 0; kk < 2; ++kk) {
            const int s = kk * 4 + kg;
            const int ra = wr * 16 + r16;
            const bf16x8 afr = *(const bf16x8*)(lA + ra * 64 + ((s ^ (ra & 7)) << 3));
#pragma unroll
            for (int ni = 0; ni < 8; ++ni) {
                const int c = wc * 128 + ni * 16 + r16;
                const bf16x8 bfr = *(const bf16x8*)(lB + c * 64 + ((s ^ (c & 7)) << 3));
                acc[ni] = __builtin_amdgcn_mfma_f32_16x16x32_bf16(afr, bfr, acc[ni], 0, 0, 0);
            }
        }
        __syncthreads();
    }

    float xv[4][8];
    float bcol[8], wcol[8], bncol[8];
#pragma unroll
    for (int ni = 0; ni < 8; ++ni) {
        const int c = wc * 128 + ni * 16 + r16;
        bcol[ni]  = bias[c];
        wcol[ni]  = lnw[c];
        bncol[ni] = lnb[c];
    }
#pragma unroll
    for (int rg = 0; rg < 4; ++rg) {
        const int row = bm + wr * 16 + kg * 4 + rg;
#pragma unroll
        for (int ni = 0; ni < 8; ++ni) {
            const int c = wc * 128 + ni * 16 + r16;
            xv[rg][ni] = tgt[(size_t)row * 256 + c] + acc[ni][rg] + bcol[ni];
        }
    }
#pragma unroll
    for (int rg = 0; rg < 4; ++rg) {
        float s = 0.f;
#pragma unroll
        for (int ni = 0; ni < 8; ++ni) s += xv[rg][ni];
#pragma unroll
        for (int m = 1; m < 16; m <<= 1) s += __shfl_xor(s, m);
        if (r16 == 0) psum[wc][wr * 16 + kg * 4 + rg] = s;
    }
    __syncthreads();
    float mu[4];
#pragma unroll
    for (int rg = 0; rg < 4; ++rg) {
        const int rl = wr * 16 + kg * 4 + rg;
        mu[rg] = (psum[0][rl] + psum[1][rl]) * (1.0f / 256.0f);
    }
#pragma unroll
    for (int rg = 0; rg < 4; ++rg) {
        float q = 0.f;
#pragma unroll
        for (int ni = 0; ni < 8; ++ni) {
            const float d = xv[rg][ni] - mu[rg];
            q += d * d;
        }
#pragma unroll
        for (int m = 1; m < 16; m <<= 1) q += __shfl_xor(q, m);
        if (r16 == 0) psq[wc][wr * 16 + kg * 4 + rg] = q;
    }
    __syncthreads();
    float onorm[4][8];
#pragma unroll
    for (int rg = 0; rg < 4; ++rg) {
        const int rl = wr * 16 + kg * 4 + rg;
        const int row = bm + rl;
        const float var = (psq[0][rl] + psq[1][rl]) * (1.0f / 256.0f);
        const float inv = 1.0f / sqrtf(var + 1e-5f);
#pragma unroll
        for (int ni = 0; ni < 8; ++ni) {
            const int c = wc * 128 + ni * 16 + r16;
            const float o = (xv[rg][ni] - mu[rg]) * inv * wcol[ni] + bncol[ni];
            onorm[rg][ni] = o;
            tgt[(size_t)row * 256 + c]  = o;
            tgtb[(size_t)row * 256 + c] = f2b(o);
        }
    }

    if (outp) {
#pragma unroll
        for (int j = 0; j < 4; ++j) {
            float wj[8];
#pragma unroll
            for (int ni = 0; ni < 8; ++ni)
                wj[ni] = ow[j * 256 + wc * 128 + ni * 16 + r16];
#pragma unroll
            for (int rg = 0; rg < 4; ++rg) {
                float p = 0.f;
#pragma unroll
                for (int ni = 0; ni < 8; ++ni) p += onorm[rg][ni] * wj[ni];
#pragma unroll
                for (int m = 1; m < 16; m <<= 1) p += __shfl_xor(p, m);
                if (r16 == 0) hsum[wc][wr * 16 + kg * 4 + rg][j] = p;
            }
        }
        __syncthreads();
        if (t < 128) {
            const int row = t >> 2, j = t & 3;
            outp[(size_t)(bm + row) * 4 + j] =
                hsum[0][row][j] + hsum[1][row][j] + ob[j];
        }
    }
}

// ---------- init tgt (fp32 + bf16) -----------------------------------------
__global__ LB void k_init_tgt(float* __restrict__ tgt, u16* __restrict__ tgtb,
                              const float* __restrict__ qe)
{
    const int e = blockIdx.x * 256 + threadIdx.x;
    const int c = e & 255;
    const int row = e >> 8;
    const int i = row & 15;
    const float v = qe[(i << 8) | c];
    tgt[e] = v;
    tgtb[e] = f2b(v);
}

// ---------- self attention v2: wave-per-head, in-wave MFMA chain (r16) -----
// grid 1024: s = blk>>1, h = (blk&1)*4 + wid. QKV bf16 [8192][768].
__global__ LB void k_self_attn(const u16* __restrict__ QKV, u16* __restrict__ O)
{
    __shared__ __align__(16) u16 arena[4][1536];   // per wave: p_lds[16][32] | vT[32][32]
    const int t = threadIdx.x;
    const int lane = t & 63, wid = t >> 6;
    const int r16 = lane & 15, kg = lane >> 4;
    const int blk = blockIdx.x;
    const int s = blk >> 1;
    const int h = (blk & 1) * 4 + wid;

    u16* p_lds = &arena[wid][0];
    u16* vT    = &arena[wid][512];

    const bf16x8 qfr = *(const bf16x8*)(QKV + (size_t)(s * 16 + r16) * 768 + h * 32 + kg * 8);
    const bf16x8 kfr = *(const bf16x8*)(QKV + (size_t)(s * 16 + r16) * 768 + 256 + h * 32 + kg * 8);
    f32x4 sv = {0.f, 0.f, 0.f, 0.f};
    sv = __builtin_amdgcn_mfma_f32_16x16x32_bf16(qfr, kfr, sv, 0, 0, 0);

    float ev[4], rowsum[4];
#pragma unroll
    for (int rg = 0; rg < 4; ++rg) ev[rg] = sv[rg] * QSCALE;
#pragma unroll
    for (int rg = 0; rg < 4; ++rg) {
        float mx = ev[rg];
#pragma unroll
        for (int m = 1; m < 16; m <<= 1) mx = fmaxf(mx, __shfl_xor(mx, m));
        ev[rg] = __expf(ev[rg] - mx);
        float ps = ev[rg];
#pragma unroll
        for (int m = 1; m < 16; m <<= 1) ps += __shfl_xor(ps, m);
        rowsum[rg] = ps;
    }

#pragma unroll
    for (int rg = 0; rg < 4; ++rg)
        p_lds[(kg * 4 + rg) * 32 + r16] = f2b(ev[rg]);
    {
        const int zq = lane & 15, zc = 16 + (lane >> 4) * 4;
#pragma unroll
        for (int j = 0; j < 4; ++j) p_lds[zq * 32 + zc + j] = 0;
    }
    {
        const int key = lane >> 2, ch8 = (lane & 3) * 8;
        const u16x8 v = *(const u16x8*)(QKV + (size_t)(s * 16 + key) * 768 + 512 + h * 32 + ch8);
#pragma unroll
        for (int j = 0; j < 8; ++j)
            vT[(ch8 + j) * 32 + key] = ((const u16*)&v)[j];
        const int zc0 = lane >> 1, zk0 = 16 + (lane & 1) * 8;
#pragma unroll
        for (int j = 0; j < 8; ++j) vT[zc0 * 32 + zk0 + j] = 0;
    }

#pragma unroll
    for (int ct = 0; ct < 2; ++ct) {
        const bf16x8 pa = *(const bf16x8*)(p_lds + r16 * 32 + kg * 8);
        const bf16x8 vb = *(const bf16x8*)(vT + (ct * 16 + r16) * 32 + kg * 8);
        f32x4 ao = {0.f, 0.f, 0.f, 0.f};
        ao = __builtin_amdgcn_mfma_f32_16x16x32_bf16(pa, vb, ao, 0, 0, 0);
#pragma unroll
        for (int rg = 0; rg < 4; ++rg) {
            const int q = kg * 4 + rg;
            O[(size_t)(s * 16 + q) * 256 + h * 32 + ct * 16 + r16] = f2b(ao[rg] / rowsum[rg]);
        }
    }
}

// ---------- cross attention v3: fused Q-proj + wave-per-head chain (r18) ---
__global__ LB void k_cross_attn(const u16* __restrict__ tgtb,
                                const u16* __restrict__ wQ,
                                const u16* __restrict__ KV, int kvs,
                                const float* __restrict__ ckv,
                                const int* __restrict__ valid,
                                const float* __restrict__ kps,
                                u16* __restrict__ O)
{
    __shared__ __align__(16) char arena[64832];
    u16* Wm  = (u16*)arena;
    u16* WmT = (u16*)(arena + 14400);

    const int t = threadIdx.x;
    const int lane = t & 63, wid = t >> 6;
    const int r16 = lane & 15, kg = lane >> 4;
    const int blk = blockIdx.x;
    const int s = blk >> 1;
    const int h = (blk & 1) * 4 + wid;
    const int b = s >> 8, n = s & 255;

    u16* buf = (u16*)(arena + 22848 + wid * 10496);
    u16* p_b = (u16*)(arena + 22848 + wid * 10496 + 2048);
    u16* QP  = p_b;

    for (int e = t; e < 16208; e += 256) ((u32*)arena)[e] = 0;
    __syncthreads();

    const float kpy = kps[(b * 256 + n) * 2 + 0];
    const float kpx = kps[(b * 256 + n) * 2 + 1];
    const float gx0 = rintf(kpx) - 7.0f;
    const float gy0 = rintf(kpy) - 7.0f;
    const float gxn0 = gx0 / 511.0f * 2.0f - 1.0f;
    const float gyn0 = gy0 / 511.0f * 2.0f - 1.0f;
    const float xb = ((gxn0 + 1.f) * 64.f - 1.f) * 0.5f;
    const float yb = ((gyn0 + 1.f) * 64.f - 1.f) * 0.5f;
    const int x0b = (int)floorf(xb);
    const int y0b = (int)floorf(yb);

    if (t < 225) {
        const int iy = t / 15, ix = t - iy * 15;
        const float gy = rintf(kpy) + (float)(iy - 7);
        const float gx = rintf(kpx) + (float)(ix - 7);
        const float gxn = gx / 511.0f * 2.0f - 1.0f;
        const float gyn = gy / 511.0f * 2.0f - 1.0f;
        const bool inval = (gxn < -1.f) || (gyn < -1.f) || (gxn > 1.f) || (gyn > 1.f);
        const float x = ((gxn + 1.f) * 64.f - 1.f) * 0.5f;
        const float y = ((gyn + 1.f) * 64.f - 1.f) * 0.5f;
        const float x0f = floorf(x), y0f = floorf(y);
        const float wx = x - x0f, wy = y - y0f;
        const int x0 = (int)x0f, y0 = (int)y0f;
#pragma unroll
        for (int tt = 0; tt < 4; ++tt) {
            const int dy = tt >> 1, dx = tt & 1;
            const int yi = y0 + dy, xi = x0 + dx;
            const bool ok = (yi >= 0) && (yi < 64) && (xi >= 0) && (xi < 64) && !inval;
            const float w = (dy ? wy : 1.f - wy) * (dx ? wx : 1.f - wx);
            if (ok) {
                const int cell = (yi - y0b) * 4 + (xi - x0b);
                const u16 wb = f2b(w);
                Wm[t * 32 + ((((cell >> 3) ^ (t & 3)) << 3) | (cell & 7))] = wb;
                WmT[cell * 264 + t] = wb;
            }
        }
    }
    // fused Q-proj: Q'[16 q][32 ch] = tgt[16,256] @ wQ_h^T + bq  (16 MFMA)
#pragma unroll
    for (int ct = 0; ct < 2; ++ct) {
        f32x4 aq = {0.f, 0.f, 0.f, 0.f};
#pragma unroll
        for (int ks = 0; ks < 8; ++ks) {
            const bf16x8 ta = *(const bf16x8*)(tgtb + (size_t)(s * 16 + r16) * 256 + ks * 32 + kg * 8);
            const bf16x8 wb = *(const bf16x8*)(wQ + (size_t)(h * 32 + ct * 16 + r16) * 256 + ks * 32 + kg * 8);
            aq = __builtin_amdgcn_mfma_f32_16x16x32_bf16(ta, wb, aq, 0, 0, 0);
        }
        const float bq = ckv[h * 32 + ct * 16 + r16];
#pragma unroll
        for (int rg = 0; rg < 4; ++rg)
            QP[(kg * 4 + rg) * 40 + ct * 16 + r16] = f2b(aq[rg] + bq);
    }
    const int cell = lane >> 2, ch8 = (lane & 3) * 8;
    const int cy = cell >> 2, cx = cell & 3;
    const int py = min(max(y0b + cy, 0), 63);
    const int px = min(max(x0b + cx, 0), 63);
    const size_t texidx = (size_t)(b * 4096 + py * 64 + px) * kvs + h * 32 + ch8;
    *(u16x8*)(buf + cell * 32 + ch8) = *(const u16x8*)(KV + texidx);
    const bool vld = valid[s] != 0;
    __syncthreads();

    // A) QT = Q' @ Tk (1 MFMA)
    {
        const bf16x8 qfr = *(const bf16x8*)(QP + r16 * 40 + kg * 8);
        const bf16x8 tfr = *(const bf16x8*)(buf + r16 * 32 + kg * 8);
        f32x4 aq = {0.f, 0.f, 0.f, 0.f};
        aq = __builtin_amdgcn_mfma_f32_16x16x32_bf16(qfr, tfr, aq, 0, 0, 0);
#pragma unroll
        for (int rg = 0; rg < 4; ++rg)
            QP[(kg * 4 + rg) * 40 + r16] = f2b(aq[rg]);
    }

    // B) S = QT @ Wm^T
    float ev[4][15];
    {
        const bf16x8 afr = *(const bf16x8*)(QP + r16 * 40 + kg * 8);
#pragma unroll
        for (int tile = 0; tile < 15; ++tile) {
            const int p = tile * 16 + r16;
            const int rc = p < 225 ? p : 224;
            const bf16x8 bfr = *(const bf16x8*)(Wm + rc * 32 + ((kg ^ (rc & 3)) << 3));
            f32x4 acc = {0.f, 0.f, 0.f, 0.f};
            acc = __builtin_amdgcn_mfma_f32_16x16x32_bf16(afr, bfr, acc, 0, 0, 0);
#pragma unroll
            for (int rg = 0; rg < 4; ++rg) {
                float sv = acc[rg] * QSCALE;
                if (p > 224) sv = -1e30f;
                if (!vld && p > 0) sv = -1e30f;
                ev[rg][tile] = sv;
            }
        }
    }
    float rowsumv[4];
#pragma unroll
    for (int rg = 0; rg < 4; ++rg) {
        float mx = -1e30f;
#pragma unroll
        for (int k = 0; k < 15; ++k) mx = fmaxf(mx, ev[rg][k]);
#pragma unroll
        for (int m = 1; m < 16; m <<= 1) mx = fmaxf(mx, __shfl_xor(mx, m));
        float ps = 0.f;
#pragma unroll
        for (int k = 0; k < 15; ++k) {
            ev[rg][k] = __expf(ev[rg][k] - mx);
            ps += ev[rg][k];
        }
#pragma unroll
        for (int m = 1; m < 16; m <<= 1) ps += __shfl_xor(ps, m);
        rowsumv[rg] = ps;
    }

    // D) P -> p_b; re-zero pad cols 225-255
#pragma unroll
    for (int rg = 0; rg < 4; ++rg)
#pragma unroll
        for (int k = 0; k < 15; ++k) {
            const int p = k * 16 + r16;
            if (p < 225) p_b[(kg * 4 + rg) * 264 + p] = f2b(ev[rg][k]);
        }
    for (int e = lane; e < 496; e += 64) {
        const int row = e / 31;
        p_b[row * 264 + 225 + (e - row * 31)] = 0;
    }

    // E) TvT into buf (overwrite Tk; zero leftover cols)
    {
        const u16x8 v = *(const u16x8*)(KV + texidx + 256);
#pragma unroll
        for (int j = 0; j < 8; ++j)
            buf[(ch8 + j) * 32 + cell] = ((const u16*)&v)[j];
        const int zr = lane & 15, zc0 = 16 + (lane >> 4) * 4;
#pragma unroll
        for (int j = 0; j < 4; ++j) buf[zr * 32 + zc0 + j] = 0;
    }

    // F) PW = P @ W (8-chain)
    f32x4 pw = {0.f, 0.f, 0.f, 0.f};
#pragma unroll
    for (int ks = 0; ks < 8; ++ks) {
        const bf16x8 pa = *(const bf16x8*)(p_b + r16 * 264 + ks * 32 + kg * 8);
        const bf16x8 wb = *(const bf16x8*)(WmT + r16 * 264 + ks * 32 + kg * 8);
        pw = __builtin_amdgcn_mfma_f32_16x16x32_bf16(pa, wb, pw, 0, 0, 0);
    }

    // G) PW -> QP; re-zero cols 16-31
#pragma unroll
    for (int rg = 0; rg < 4; ++rg)
        QP[(kg * 4 + rg) * 40 + r16] = f2b(pw[rg]);
    {
        const int zq = lane & 15, zc0 = 16 + (lane >> 4) * 4;
#pragma unroll
        for (int j = 0; j < 4; ++j) QP[zq * 40 + zc0 + j] = 0;
    }

    // H) O = PW @ Tv^T ; I) /rowsum + cv, write
#pragma unroll
    for (int ct = 0; ct < 2; ++ct) {
        const bf16x8 pa = *(const bf16x8*)(QP + r16 * 40 + kg * 8);
        const bf16x8 vb = *(const bf16x8*)(buf + (ct * 16 + r16) * 32 + kg * 8);
        f32x4 ao = {0.f, 0.f, 0.f, 0.f};
        ao = __builtin_amdgcn_mfma_f32_16x16x32_bf16(pa, vb, ao, 0, 0, 0);
#pragma unroll
        for (int rg = 0; rg < 4; ++rg) {
            const int q = kg * 4 + rg;
            const int ch = h * 32 + ct * 16 + r16;
            const float val = ao[rg] / rowsumv[rg] + ckv[256 + ch];
            O[(size_t)(s * 16 + q) * 256 + ch] = f2b(val);
        }
    }
}

// ---------------------------------------------------------------------------
extern "C" void kernel_launch(void* const* d_in, const int* in_sizes, int n_in,
                              void* d_out, int out_size, void* d_ws, size_t ws_size,
                              hipStream_t stream)
{
    const float* img          = (const float*)d_in[0];
    const float* kps          = (const float*)d_in[1];
    const unsigned char* vmsk = (const unsigned char*)d_in[2];
    const float* proj_w       = (const float*)d_in[3];
    const float* proj_b       = (const float*)d_in[4];
    const float* query_embed  = (const float*)d_in[5];
    const float* self_qkv_w   = (const float*)d_in[6];
    const float* self_qkv_b   = (const float*)d_in[7];
    const float* self_out_w   = (const float*)d_in[8];
    const float* self_out_b   = (const float*)d_in[9];
    const float* cross_qkv_w  = (const float*)d_in[10];
    const float* cross_qkv_b  = (const float*)d_in[11];
    const float* cross_out_w  = (const float*)d_in[12];
    const float* cross_out_b  = (const float*)d_in[13];
    const float* ffn1_w       = (const float*)d_in[14];
    const float* ffn1_b       = (const float*)d_in[15];
    const float* ffn2_w       = (const float*)d_in[16];
    const float* ffn2_b       = (const float*)d_in[17];
    const float* ln1_w        = (const float*)d_in[18];
    const float* ln1_b        = (const float*)d_in[19];
    const float* ln2_w        = (const float*)d_in[20];
    const float* ln2_b        = (const float*)d_in[21];
    const float* ln3_w        = (const float*)d_in[22];
    const float* ln3_b        = (const float*)d_in[23];
    const float* out_w        = (const float*)d_in[24];
    const float* out_b        = (const float*)d_in[25];
    float* out = (float*)d_out;

    // ---- workspace layout (~80 MB) ----
    char* W8 = (char*)d_ws;
    size_t off = 0;
    auto alloc = [&](size_t bytes) { void* p = W8 + off; off += (bytes + 255) & ~(size_t)255; return p; };
    float* tgt   = (float*)alloc(2097152 * 4);
    u16* Sb16    = (u16*)alloc(6291456 * 2);     // self-QKV bf16 [8192][768]
    float* ckv   = (float*)alloc(3 * 512 * 4);
    u16* imgTb   = (u16*)alloc(2097152 * 2);
    u16* KVb3    = (u16*)alloc(12582912 * 2);    // [8192][1536] all 3 layers K|V
    u16* tgtb    = (u16*)alloc(2097152 * 2);
    u16* Abuf    = (u16*)alloc(2097152 * 2);
    u16* Hbuf    = (u16*)alloc(8388608 * 2);
    u16* wAll    = (u16*)alloc(3670016 * 2);
    u16* WcombB  = (u16*)alloc(393216 * 2);      // (wCKV3 @ proj) weights
    int* valid   = (int*)alloc(512 * 4);

    u16* wProj  = wAll;             // 65536 (layout keeper)
    u16* wSQKV  = wProj + 65536;    // 3*768*256
    u16* wSOut  = wSQKV + 589824;   // 3*256*256
    u16* wCQKV  = wSOut + 196608;   // 3*768*256 (rows 0-255 of each layer = Wq)
    u16* wCOut  = wCQKV + 589824;   // 3*256*256
    u16* wF1    = wCOut + 196608;   // 3*1024*256
    u16* wF2    = wF1 + 786432;     // 3*256*1024
    u16* wCKV3  = wF2 + 786432;     // 3*512*256 cross K|V weights
    u16* wProjT = wCKV3 + 393216;   // 256*256 proj^T

    k_wconv<<<14340, 256, 0, stream>>>(proj_w, self_qkv_w, self_out_w, cross_qkv_w,
                                       cross_out_w, ffn1_w, ffn2_w, wAll,
                                       vmsk, valid, proj_b, cross_qkv_b, ckv);
    k_transpose<<<dim3(64, 4, 2), 256, 0, stream>>>(img, imgTb);
    gemm_mfma<64><<<dim3(2, 24), 256, 0, stream>>>(wCKV3, wProjT, nullptr,
                                                   nullptr, WcombB, 1536, 256, 256, 0);
    gemm_mfma<64><<<dim3(12, 128), 256, 0, stream>>>(imgTb, WcombB, nullptr,
                                                     nullptr, KVb3, 8192, 1536, 256, 0);
    k_init_tgt<<<8192, 256, 0, stream>>>(tgt, tgtb, query_embed);

    for (int l = 0; l < 3; ++l) {
        const int last = (l == 2);
        // ---- self attention (GEMM projection; v2 attention) ----
        gemm_mfma<64><<<dim3(6, 128), 256, 0, stream>>>(tgtb, wSQKV + (size_t)l * 196608,
            self_qkv_b + (size_t)l * 768, nullptr, Sb16, 8192, 768, 256, 0);
        k_self_attn<<<1024, 256, 0, stream>>>(Sb16, Abuf);
        gemm_ln<<<256, 256, 0, stream>>>(Abuf, wSOut + (size_t)l * 65536,
            self_out_b + (size_t)l * 256, tgt, tgtb,
            ln1_w + (size_t)l * 256, ln1_b + (size_t)l * 256, 256,
            nullptr, nullptr, nullptr);

        // ---- cross attention (Q-proj fused in-wave) ----
        k_cross_attn<<<1024, 256, 0, stream>>>(tgtb, wCQKV + (size_t)l * 196608,
                                               KVb3 + (size_t)l * 512, 1536,
                                               ckv + (size_t)l * 512, valid, kps, Abuf);
        gemm_ln<<<256, 256, 0, stream>>>(Abuf, wCOut + (size_t)l * 65536,
            cross_out_b + (size_t)l * 256, tgt, tgtb,
            ln2_w + (size_t)l * 256, ln2_b + (size_t)l * 256, 256,
            nullptr, nullptr, nullptr);

        // ---- FFN (final layer fuses the output head) ----
        gemm_mfma<64><<<dim3(8, 128), 256, 0, stream>>>(tgtb, wF1 + (size_t)l * 262144,
            ffn1_b + (size_t)l * 1024, nullptr, Hbuf, 8192, 1024, 256, 1);
        gemm_ln<<<256, 256, 0, stream>>>(Hbuf, wF2 + (size_t)l * 262144,
            ffn2_b + (size_t)l * 256, tgt, tgtb,
            ln3_w + (size_t)l * 256, ln3_b + (size_t)l * 256, 1024,
            last ? out_w : nullptr, last ? out_b : nullptr, last ? out : nullptr);
    }
}

// Round 21
// 353.722 us; speedup vs baseline: 1.1496x; 1.0328x over previous
//
#include <hip/hip_runtime.h>
#include <hip/hip_fp16.h>

#define LB __launch_bounds__(256)

typedef unsigned short u16;
typedef unsigned int   u32;
typedef __attribute__((ext_vector_type(8))) short bf16x8;   // 8 bf16 (4 VGPRs)
typedef __attribute__((ext_vector_type(4))) float f32x4;
typedef __attribute__((ext_vector_type(8))) u16  u16x8;

__device__ __forceinline__ u16 f2b(float f) {
    u32 u = __float_as_uint(f);
    u32 r = (u + 0x7fffu + ((u >> 16) & 1u)) >> 16;
    return (u16)r;
}
__device__ __forceinline__ float b2f(u16 h) {
    return __uint_as_float((u32)h << 16);
}

#define QSCALE 0.17677669529663687f

// ---------------------------------------------------------------------------
// B=2 N=256 C=256 HF=WF=64 ROI=15(225) HID=256 HEADS=8 Dh=32 DEPTH=3 FFN=1024
// NQ=16 -> seqs S=512, MT=8192.
// r21: cross-attn grid 1024 -> 512 (one block per keypoint; each wave runs
// TWO head chains sequentially, reusing wave-local LDS). Arena-zero + W-build
// once per keypoint (was 2x); all 512 blocks resident in one round.
// LDS-lifetime audit: h1 Tk rewrites buf rows0-15; buf rows16-31 cols16-31
// keep arena-zero; h1 D-phase re-zeroes p_b pads; QP cols32-39 never read.
// ---------------------------------------------------------------------------

// ---------- weights fp32 -> bf16 arena + repack + (tail blocks) prep -------
__global__ LB void k_wconv(const float* __restrict__ s0, const float* __restrict__ s1,
                           const float* __restrict__ s2, const float* __restrict__ s3,
                           const float* __restrict__ s4, const float* __restrict__ s5,
                           const float* __restrict__ s6, u16* __restrict__ dst,
                           const unsigned char* __restrict__ m, int* __restrict__ valid,
                           const float* __restrict__ pb,
                           const float* __restrict__ cqkv_b,
                           float* __restrict__ ckv)
{
    if (blockIdx.x >= 14336) {
        const int pblk = blockIdx.x - 14336;
        if (pblk == 0) {
            __shared__ int flag;
            if (threadIdx.x == 0) flag = 0;
            __syncthreads();
            int loc = 0;
            for (int off = threadIdx.x; off < 512; off += 256)
                if ((off & 3) != 0 && m[off] != 0) loc = 1;
            if (loc) atomicOr(&flag, 1);
            __syncthreads();
            const bool bytelay = (flag != 0);
            for (int s = threadIdx.x; s < 512; s += 256)
                valid[s] = bytelay ? (int)(m[s] != 0) : (int)(((const int*)m)[s] != 0);
        } else {
            const int l = pblk - 1;   // 0..2
            const float* Wv = s3 + (size_t)l * 196608 + 131072;
            const float* vb = cqkv_b + (size_t)l * 768 + 512;
            const int o = threadIdx.x;
            float c = 0.f;
            for (int cc = 0; cc < 256; cc += 4) {
                const float4 p4 = *(const float4*)(pb + cc);
                const float4 v4 = *(const float4*)(Wv + (size_t)o * 256 + cc);
                c += p4.x * v4.x + p4.y * v4.y + p4.z * v4.z + p4.w * v4.w;
            }
            ckv[l * 512 + o]       = cqkv_b[(size_t)l * 768 + o];  // bq (fused Q-proj)
            ckv[l * 512 + 256 + o] = c + vb[o];                    // cv (epilogue)
        }
        return;
    }
    const int e = blockIdx.x * 256 + threadIdx.x;
    if (e >= 3670016) return;
    float v;
    int i = e;
    if (i < 65536) v = s0[i];
    else if ((i -= 65536) < 589824) v = s1[i];
    else if ((i -= 589824) < 196608) v = s2[i];
    else if ((i -= 196608) < 589824) v = s3[i];
    else if ((i -= 589824) < 196608) v = s4[i];
    else if ((i -= 196608) < 786432) v = s5[i];
    else if ((i -= 786432) < 786432) v = s6[i];
    else if ((i -= 786432) < 393216) {  // wCKV3: [l][512 rows (Wk|Wv)][256]
        const int l = i / 131072;
        const int r = (i - l * 131072) >> 8;
        const int c = i & 255;
        v = s3[(size_t)l * 196608 + (size_t)(256 + r) * 256 + c];
    } else {                            // projT: [c][o] = proj_w[o][c]
        i -= 393216;
        v = s0[(i & 255) * 256 + (i >> 8)];
    }
    dst[e] = f2b(v);
}

// ---------- transpose image (B,C,64,64) -> (B,4096,C) bf16 -----------------
__global__ LB void k_transpose(const float* __restrict__ img, u16* __restrict__ imgTb)
{
    __shared__ float tile[64][65];
    const int b  = blockIdx.z;
    const int c0 = blockIdx.y * 64;
    const int p0 = blockIdx.x * 64;
    const int t  = threadIdx.x;
    const int tr = t >> 6, tc = t & 63;
#pragma unroll
    for (int p = 0; p < 16; ++p) {
        const int i = p * 4 + tr;
        tile[i][tc] = img[((size_t)(b * 256 + c0 + i)) * 4096 + p0 + tc];
    }
    __syncthreads();
#pragma unroll
    for (int p = 0; p < 16; ++p) {
        const int jj = p * 4 + tr;
        imgTb[((size_t)(b * 4096 + p0 + jj)) * 256 + c0 + tc] = f2b(tile[tc][jj]);
    }
}

// ---------- bf16 MFMA GEMM: C[M,N] = A[M,K](bf16) @ W[N,K](bf16)^T + bias --
template<int BM>
__global__ LB void gemm_mfma(const u16* __restrict__ A, const u16* __restrict__ W,
                             const float* __restrict__ bias,
                             float* __restrict__ Cf, u16* __restrict__ Cb,
                             int M, int N, int K, int relu)
{
    constexpr int BN = 128;
    __shared__ u16 lds[2][(BM + BN) * 64];
    const int t = threadIdx.x;
    const int wid = t >> 6, lane = t & 63;
    const int bm = blockIdx.y * BM, bn = blockIdx.x * BN;
    const int KT = K >> 6;

    auto stage = [&](int buf, int kt) {
        const int k0 = kt * 64;
        const int rr = t >> 3;
        const int u  = t & 7;
#pragma unroll
        for (int q = 0; q < BM / 32; ++q) {
            const int r = q * 32 + rr;
            const u16* src = A + (size_t)(bm + r) * K + k0 + ((u ^ (r & 7)) << 3);
            __builtin_amdgcn_global_load_lds(
                (const __attribute__((address_space(1))) void*)src,
                (__attribute__((address_space(3))) void*)&lds[buf][q * 2048 + wid * 512],
                16, 0, 0);
        }
#pragma unroll
        for (int q = 0; q < 4; ++q) {
            const int r = q * 32 + rr;
            const u16* src = W + (size_t)(bn + r) * K + k0 + ((u ^ (r & 7)) << 3);
            __builtin_amdgcn_global_load_lds(
                (const __attribute__((address_space(1))) void*)src,
                (__attribute__((address_space(3))) void*)&lds[buf][BM * 64 + q * 2048 + wid * 512],
                16, 0, 0);
        }
    };

    const int wr = wid >> 1, wc = wid & 1;
    constexpr int MR = BM / 32;
    f32x4 acc[MR][4];
    const f32x4 z = {0.f, 0.f, 0.f, 0.f};
#pragma unroll
    for (int mi = 0; mi < MR; ++mi)
#pragma unroll
        for (int ni = 0; ni < 4; ++ni) acc[mi][ni] = z;

    const int r16 = lane & 15, kg = lane >> 4;

    stage(0, 0);
    int cur = 0;
    for (int kt = 0; kt < KT; ++kt) {
        asm volatile("s_waitcnt vmcnt(0)" ::: "memory");
        __syncthreads();
        if (kt + 1 < KT) stage(cur ^ 1, kt + 1);
        const u16* pA = lds[cur];
        const u16* pB = lds[cur] + BM * 64;
#pragma unroll
        for (int kk = 0; kk < 2; ++kk) {
            const int s = kk * 4 + kg;
            bf16x8 afr[MR], bfr[4];
#pragma unroll
            for (int mi = 0; mi < MR; ++mi) {
                const int r = wr * (BM / 2) + mi * 16 + r16;
                afr[mi] = *(const bf16x8*)(pA + r * 64 + ((s ^ (r & 7)) << 3));
            }
#pragma unroll
            for (int ni = 0; ni < 4; ++ni) {
                const int c = wc * 64 + ni * 16 + r16;
                bfr[ni] = *(const bf16x8*)(pB + c * 64 + ((s ^ (c & 7)) << 3));
            }
#pragma unroll
            for (int mi = 0; mi < MR; ++mi)
#pragma unroll
                for (int ni = 0; ni < 4; ++ni)
                    acc[mi][ni] = __builtin_amdgcn_mfma_f32_16x16x32_bf16(
                        afr[mi], bfr[ni], acc[mi][ni], 0, 0, 0);
        }
        cur ^= 1;
    }

#pragma unroll
    for (int mi = 0; mi < MR; ++mi) {
#pragma unroll
        for (int ni = 0; ni < 4; ++ni) {
            const int col = bn + wc * 64 + ni * 16 + r16;
            const float bs = bias ? bias[col] : 0.0f;
#pragma unroll
            for (int rg = 0; rg < 4; ++rg) {
                const int row = bm + wr * (BM / 2) + mi * 16 + kg * 4 + rg;
                float v = acc[mi][ni][rg] + bs;
                if (relu) v = fmaxf(v, 0.0f);
                if (Cf) Cf[(size_t)row * N + col] = v;
                if (Cb) Cb[(size_t)row * N + col] = f2b(v);
            }
        }
    }
}

// ---------- fused GEMM + residual + LayerNorm (+ optional output head) -----
__global__ LB void gemm_ln(const u16* __restrict__ A, const u16* __restrict__ W,
                           const float* __restrict__ bias,
                           float* __restrict__ tgt, u16* __restrict__ tgtb,
                           const float* __restrict__ lnw, const float* __restrict__ lnb,
                           int K,
                           const float* __restrict__ ow, const float* __restrict__ ob,
                           float* __restrict__ outp)
{
    __shared__ u16 lA[32 * 64];
    __shared__ u16 lB[256 * 64];
    __shared__ float psum[2][32];
    __shared__ float psq[2][32];
    __shared__ float hsum[2][32][4];
    const int t = threadIdx.x;
    const int wid = t >> 6, lane = t & 63;
    const int r16 = lane & 15, kg = lane >> 4;
    const int wr = wid >> 1, wc = wid & 1;
    const int bm = blockIdx.x * 32;
    const int KT = K >> 6;

    f32x4 acc[8];
    const f32x4 z = {0.f, 0.f, 0.f, 0.f};
#pragma unroll
    for (int ni = 0; ni < 8; ++ni) acc[ni] = z;

    for (int kt = 0; kt < KT; ++kt) {
        const int k0 = kt * 64;
        const int rr = t >> 3;
        const int u  = t & 7;
        {
            const int r = rr;
            const u16* src = A + (size_t)(bm + r) * K + k0 + ((u ^ (r & 7)) << 3);
            __builtin_amdgcn_global_load_lds(
                (const __attribute__((address_space(1))) void*)src,
                (__attribute__((address_space(3))) void*)&lA[wid * 512],
                16, 0, 0);
        }
#pragma unroll
        for (int q = 0; q < 8; ++q) {
            const int r = q * 32 + rr;
            const u16* src = W + (size_t)r * K + k0 + ((u ^ (r & 7)) << 3);
            __builtin_amdgcn_global_load_lds(
                (const __attribute__((address_space(1))) void*)src,
                (__attribute__((address_space(3))) void*)&lB[q * 2048 + wid * 512],
                16, 0, 0);
        }
        asm volatile("s_waitcnt vmcnt(0)" ::: "memory");
        __syncthreads();
#pragma unroll
        for (int kk = 0; kk < 2; ++kk) {
            const int s = kk * 4 + kg;
            const int ra = wr * 16 + r16;
            const bf16x8 afr = *(const bf16x8*)(lA + ra * 64 + ((s ^ (ra & 7)) << 3));
#pragma unroll
            for (int ni = 0; ni < 8; ++ni) {
                const int c = wc * 128 + ni * 16 + r16;
                const bf16x8 bfr = *(const bf16x8*)(lB + c * 64 + ((s ^ (c & 7)) << 3));
                acc[ni] = __builtin_amdgcn_mfma_f32_16x16x32_bf16(afr, bfr, acc[ni], 0, 0, 0);
            }
        }
        __syncthreads();
    }

    float xv[4][8];
    float bcol[8], wcol[8], bncol[8];
#pragma unroll
    for (int ni = 0; ni < 8; ++ni) {
        const int c = wc * 128 + ni * 16 + r16;
        bcol[ni]  = bias[c];
        wcol[ni]  = lnw[c];
        bncol[ni] = lnb[c];
    }
#pragma unroll
    for (int rg = 0; rg < 4; ++rg) {
        const int row = bm + wr * 16 + kg * 4 + rg;
#pragma unroll
        for (int ni = 0; ni < 8; ++ni) {
            const int c = wc * 128 + ni * 16 + r16;
            xv[rg][ni] = tgt[(size_t)row * 256 + c] + acc[ni][rg] + bcol[ni];
        }
    }
#pragma unroll
    for (int rg = 0; rg < 4; ++rg) {
        float s = 0.f;
#pragma unroll
        for (int ni = 0; ni < 8; ++ni) s += xv[rg][ni];
#pragma unroll
        for (int m = 1; m < 16; m <<= 1) s += __shfl_xor(s, m);
        if (r16 == 0) psum[wc][wr * 16 + kg * 4 + rg] = s;
    }
    __syncthreads();
    float mu[4];
#pragma unroll
    for (int rg = 0; rg < 4; ++rg) {
        const int rl = wr * 16 + kg * 4 + rg;
        mu[rg] = (psum[0][rl] + psum[1][rl]) * (1.0f / 256.0f);
    }
#pragma unroll
    for (int rg = 0; rg < 4; ++rg) {
        float q = 0.f;
#pragma unroll
        for (int ni = 0; ni < 8; ++ni) {
            const float d = xv[rg][ni] - mu[rg];
            q += d * d;
        }
#pragma unroll
        for (int m = 1; m < 16; m <<= 1) q += __shfl_xor(q, m);
        if (r16 == 0) psq[wc][wr * 16 + kg * 4 + rg] = q;
    }
    __syncthreads();
    float onorm[4][8];
#pragma unroll
    for (int rg = 0; rg < 4; ++rg) {
        const int rl = wr * 16 + kg * 4 + rg;
        const int row = bm + rl;
        const float var = (psq[0][rl] + psq[1][rl]) * (1.0f / 256.0f);
        const float inv = 1.0f / sqrtf(var + 1e-5f);
#pragma unroll
        for (int ni = 0; ni < 8; ++ni) {
            const int c = wc * 128 + ni * 16 + r16;
            const float o = (xv[rg][ni] - mu[rg]) * inv * wcol[ni] + bncol[ni];
            onorm[rg][ni] = o;
            tgt[(size_t)row * 256 + c]  = o;
            tgtb[(size_t)row * 256 + c] = f2b(o);
        }
    }

    if (outp) {
#pragma unroll
        for (int j = 0; j < 4; ++j) {
            float wj[8];
#pragma unroll
            for (int ni = 0; ni < 8; ++ni)
                wj[ni] = ow[j * 256 + wc * 128 + ni * 16 + r16];
#pragma unroll
            for (int rg = 0; rg < 4; ++rg) {
                float p = 0.f;
#pragma unroll
                for (int ni = 0; ni < 8; ++ni) p += onorm[rg][ni] * wj[ni];
#pragma unroll
                for (int m = 1; m < 16; m <<= 1) p += __shfl_xor(p, m);
                if (r16 == 0) hsum[wc][wr * 16 + kg * 4 + rg][j] = p;
            }
        }
        __syncthreads();
        if (t < 128) {
            const int row = t >> 2, j = t & 3;
            outp[(size_t)(bm + row) * 4 + j] =
                hsum[0][row][j] + hsum[1][row][j] + ob[j];
        }
    }
}

// ---------- init tgt (fp32 + bf16) -----------------------------------------
__global__ LB void k_init_tgt(float* __restrict__ tgt, u16* __restrict__ tgtb,
                              const float* __restrict__ qe)
{
    const int e = blockIdx.x * 256 + threadIdx.x;
    const int c = e & 255;
    const int row = e >> 8;
    const int i = row & 15;
    const float v = qe[(i << 8) | c];
    tgt[e] = v;
    tgtb[e] = f2b(v);
}

// ---------- self attention v2: wave-per-head, in-wave MFMA chain (r16) -----
__global__ LB void k_self_attn(const u16* __restrict__ QKV, u16* __restrict__ O)
{
    __shared__ __align__(16) u16 arena[4][1536];   // per wave: p_lds[16][32] | vT[32][32]
    const int t = threadIdx.x;
    const int lane = t & 63, wid = t >> 6;
    const int r16 = lane & 15, kg = lane >> 4;
    const int blk = blockIdx.x;
    const int s = blk >> 1;
    const int h = (blk & 1) * 4 + wid;

    u16* p_lds = &arena[wid][0];
    u16* vT    = &arena[wid][512];

    const bf16x8 qfr = *(const bf16x8*)(QKV + (size_t)(s * 16 + r16) * 768 + h * 32 + kg * 8);
    const bf16x8 kfr = *(const bf16x8*)(QKV + (size_t)(s * 16 + r16) * 768 + 256 + h * 32 + kg * 8);
    f32x4 sv = {0.f, 0.f, 0.f, 0.f};
    sv = __builtin_amdgcn_mfma_f32_16x16x32_bf16(qfr, kfr, sv, 0, 0, 0);

    float ev[4], rowsum[4];
#pragma unroll
    for (int rg = 0; rg < 4; ++rg) ev[rg] = sv[rg] * QSCALE;
#pragma unroll
    for (int rg = 0; rg < 4; ++rg) {
        float mx = ev[rg];
#pragma unroll
        for (int m = 1; m < 16; m <<= 1) mx = fmaxf(mx, __shfl_xor(mx, m));
        ev[rg] = __expf(ev[rg] - mx);
        float ps = ev[rg];
#pragma unroll
        for (int m = 1; m < 16; m <<= 1) ps += __shfl_xor(ps, m);
        rowsum[rg] = ps;
    }

#pragma unroll
    for (int rg = 0; rg < 4; ++rg)
        p_lds[(kg * 4 + rg) * 32 + r16] = f2b(ev[rg]);
    {
        const int zq = lane & 15, zc = 16 + (lane >> 4) * 4;
#pragma unroll
        for (int j = 0; j < 4; ++j) p_lds[zq * 32 + zc + j] = 0;
    }
    {
        const int key = lane >> 2, ch8 = (lane & 3) * 8;
        const u16x8 v = *(const u16x8*)(QKV + (size_t)(s * 16 + key) * 768 + 512 + h * 32 + ch8);
#pragma unroll
        for (int j = 0; j < 8; ++j)
            vT[(ch8 + j) * 32 + key] = ((const u16*)&v)[j];
        const int zc0 = lane >> 1, zk0 = 16 + (lane & 1) * 8;
#pragma unroll
        for (int j = 0; j < 8; ++j) vT[zc0 * 32 + zk0 + j] = 0;
    }

#pragma unroll
    for (int ct = 0; ct < 2; ++ct) {
        const bf16x8 pa = *(const bf16x8*)(p_lds + r16 * 32 + kg * 8);
        const bf16x8 vb = *(const bf16x8*)(vT + (ct * 16 + r16) * 32 + kg * 8);
        f32x4 ao = {0.f, 0.f, 0.f, 0.f};
        ao = __builtin_amdgcn_mfma_f32_16x16x32_bf16(pa, vb, ao, 0, 0, 0);
#pragma unroll
        for (int rg = 0; rg < 4; ++rg) {
            const int q = kg * 4 + rg;
            O[(size_t)(s * 16 + q) * 256 + h * 32 + ct * 16 + r16] = f2b(ao[rg] / rowsum[rg]);
        }
    }
}

// ---------- cross attention v4: one block per keypoint, 2 heads per wave ---
__global__ LB void k_cross_attn(const u16* __restrict__ tgtb,
                                const u16* __restrict__ wQ,
                                const u16* __restrict__ KV, int kvs,
                                const float* __restrict__ ckv,
                                const int* __restrict__ valid,
                                const float* __restrict__ kps,
                                u16* __restrict__ O)
{
    __shared__ __align__(16) char arena[64832];
    u16* Wm  = (u16*)arena;
    u16* WmT = (u16*)(arena + 14400);

    const int t = threadIdx.x;
    const int lane = t & 63, wid = t >> 6;
    const int r16 = lane & 15, kg = lane >> 4;
    const int s = blockIdx.x;              // one block per keypoint
    const int b = s >> 8, n = s & 255;

    u16* buf = (u16*)(arena + 22848 + wid * 10496);           // [32][32]
    u16* p_b = (u16*)(arena + 22848 + wid * 10496 + 2048);    // [16][264]
    u16* QP  = p_b;                                            // [16][40] overlay

    for (int e = t; e < 16208; e += 256) ((u32*)arena)[e] = 0;
    __syncthreads();

    const float kpy = kps[(b * 256 + n) * 2 + 0];
    const float kpx = kps[(b * 256 + n) * 2 + 1];
    const float gx0 = rintf(kpx) - 7.0f;
    const float gy0 = rintf(kpy) - 7.0f;
    const float gxn0 = gx0 / 511.0f * 2.0f - 1.0f;
    const float gyn0 = gy0 / 511.0f * 2.0f - 1.0f;
    const float xb = ((gxn0 + 1.f) * 64.f - 1.f) * 0.5f;
    const float yb = ((gyn0 + 1.f) * 64.f - 1.f) * 0.5f;
    const int x0b = (int)floorf(xb);
    const int y0b = (int)floorf(yb);

    // ---- W build once per keypoint ----
    if (t < 225) {
        const int iy = t / 15, ix = t - iy * 15;
        const float gy = rintf(kpy) + (float)(iy - 7);
        const float gx = rintf(kpx) + (float)(ix - 7);
        const float gxn = gx / 511.0f * 2.0f - 1.0f;
        const float gyn = gy / 511.0f * 2.0f - 1.0f;
        const bool inval = (gxn < -1.f) || (gyn < -1.f) || (gxn > 1.f) || (gyn > 1.f);
        const float x = ((gxn + 1.f) * 64.f - 1.f) * 0.5f;
        const float y = ((gyn + 1.f) * 64.f - 1.f) * 0.5f;
        const float x0f = floorf(x), y0f = floorf(y);
        const float wx = x - x0f, wy = y - y0f;
        const int x0 = (int)x0f, y0 = (int)y0f;
#pragma unroll
        for (int tt = 0; tt < 4; ++tt) {
            const int dy = tt >> 1, dx = tt & 1;
            const int yi = y0 + dy, xi = x0 + dx;
            const bool ok = (yi >= 0) && (yi < 64) && (xi >= 0) && (xi < 64) && !inval;
            const float w = (dy ? wy : 1.f - wy) * (dx ? wx : 1.f - wx);
            if (ok) {
                const int cell = (yi - y0b) * 4 + (xi - x0b);
                const u16 wb = f2b(w);
                Wm[t * 32 + ((((cell >> 3) ^ (t & 3)) << 3) | (cell & 7))] = wb;
                WmT[cell * 264 + t] = wb;
            }
        }
    }

    const int cell = lane >> 2, ch8 = (lane & 3) * 8;
    const int cy = cell >> 2, cx = cell & 3;
    const int py = min(max(y0b + cy, 0), 63);
    const int px = min(max(x0b + cx, 0), 63);
    const bool vld = valid[s] != 0;

    // ---- two heads per wave: h = wid (hh=0), wid+4 (hh=1) ----
    for (int hh = 0; hh < 2; ++hh) {
        const int h = hh * 4 + wid;
        const size_t texidx = (size_t)(b * 4096 + py * 64 + px) * kvs + h * 32 + ch8;

        // fused Q-proj: Q'[16 q][32 ch] = tgt @ wQ_h^T + bq  (16 MFMA)
#pragma unroll
        for (int ct = 0; ct < 2; ++ct) {
            f32x4 aq = {0.f, 0.f, 0.f, 0.f};
#pragma unroll
            for (int ks = 0; ks < 8; ++ks) {
                const bf16x8 ta = *(const bf16x8*)(tgtb + (size_t)(s * 16 + r16) * 256 + ks * 32 + kg * 8);
                const bf16x8 wb = *(const bf16x8*)(wQ + (size_t)(h * 32 + ct * 16 + r16) * 256 + ks * 32 + kg * 8);
                aq = __builtin_amdgcn_mfma_f32_16x16x32_bf16(ta, wb, aq, 0, 0, 0);
            }
            const float bq = ckv[h * 32 + ct * 16 + r16];
#pragma unroll
            for (int rg = 0; rg < 4; ++rg)
                QP[(kg * 4 + rg) * 40 + ct * 16 + r16] = f2b(aq[rg] + bq);
        }
        // Tk load (wave-local; rows 0-15 x all 32 cols)
        *(u16x8*)(buf + cell * 32 + ch8) = *(const u16x8*)(KV + texidx);

        if (hh == 0) __syncthreads();   // Wm/WmT visible before first S

        // A) QT = Q' @ Tk (1 MFMA)
        {
            const bf16x8 qfr = *(const bf16x8*)(QP + r16 * 40 + kg * 8);
            const bf16x8 tfr = *(const bf16x8*)(buf + r16 * 32 + kg * 8);
            f32x4 aq = {0.f, 0.f, 0.f, 0.f};
            aq = __builtin_amdgcn_mfma_f32_16x16x32_bf16(qfr, tfr, aq, 0, 0, 0);
#pragma unroll
            for (int rg = 0; rg < 4; ++rg)
                QP[(kg * 4 + rg) * 40 + r16] = f2b(aq[rg]);
        }

        // B) S = QT @ Wm^T ; C) in-register softmax
        float ev[4][15];
        {
            const bf16x8 afr = *(const bf16x8*)(QP + r16 * 40 + kg * 8);
#pragma unroll
            for (int tile = 0; tile < 15; ++tile) {
                const int p = tile * 16 + r16;
                const int rc = p < 225 ? p : 224;
                const bf16x8 bfr = *(const bf16x8*)(Wm + rc * 32 + ((kg ^ (rc & 3)) << 3));
                f32x4 acc = {0.f, 0.f, 0.f, 0.f};
                acc = __builtin_amdgcn_mfma_f32_16x16x32_bf16(afr, bfr, acc, 0, 0, 0);
#pragma unroll
                for (int rg = 0; rg < 4; ++rg) {
                    float sv = acc[rg] * QSCALE;
                    if (p > 224) sv = -1e30f;
                    if (!vld && p > 0) sv = -1e30f;
                    ev[rg][tile] = sv;
                }
            }
        }
        float rowsumv[4];
#pragma unroll
        for (int rg = 0; rg < 4; ++rg) {
            float mx = -1e30f;
#pragma unroll
            for (int k = 0; k < 15; ++k) mx = fmaxf(mx, ev[rg][k]);
#pragma unroll
            for (int m = 1; m < 16; m <<= 1) mx = fmaxf(mx, __shfl_xor(mx, m));
            float ps = 0.f;
#pragma unroll
            for (int k = 0; k < 15; ++k) {
                ev[rg][k] = __expf(ev[rg][k] - mx);
                ps += ev[rg][k];
            }
#pragma unroll
            for (int m = 1; m < 16; m <<= 1) ps += __shfl_xor(ps, m);
            rowsumv[rg] = ps;
        }

        // D) P -> p_b; re-zero pad cols 225-255
#pragma unroll
        for (int rg = 0; rg < 4; ++rg)
#pragma unroll
            for (int k = 0; k < 15; ++k) {
                const int p = k * 16 + r16;
                if (p < 225) p_b[(kg * 4 + rg) * 264 + p] = f2b(ev[rg][k]);
            }
        for (int e = lane; e < 496; e += 64) {
            const int row = e / 31;
            p_b[row * 264 + 225 + (e - row * 31)] = 0;
        }

        // E) TvT into buf (overwrite Tk; zero leftover cols rows 0-15)
        {
            const u16x8 v = *(const u16x8*)(KV + texidx + 256);
#pragma unroll
            for (int j = 0; j < 8; ++j)
                buf[(ch8 + j) * 32 + cell] = ((const u16*)&v)[j];
            const int zr = lane & 15, zc0 = 16 + (lane >> 4) * 4;
#pragma unroll
            for (int j = 0; j < 4; ++j) buf[zr * 32 + zc0 + j] = 0;
        }

        // F) PW = P @ W (8-chain)
        f32x4 pw = {0.f, 0.f, 0.f, 0.f};
#pragma unroll
        for (int ks = 0; ks < 8; ++ks) {
            const bf16x8 pa = *(const bf16x8*)(p_b + r16 * 264 + ks * 32 + kg * 8);
            const bf16x8 wb = *(const bf16x8*)(WmT + r16 * 264 + ks * 32 + kg * 8);
            pw = __builtin_amdgcn_mfma_f32_16x16x32_bf16(pa, wb, pw, 0, 0, 0);
        }

        // G) PW -> QP; re-zero cols 16-31
#pragma unroll
        for (int rg = 0; rg < 4; ++rg)
            QP[(kg * 4 + rg) * 40 + r16] = f2b(pw[rg]);
        {
            const int zq = lane & 15, zc0 = 16 + (lane >> 4) * 4;
#pragma unroll
            for (int j = 0; j < 4; ++j) QP[zq * 40 + zc0 + j] = 0;
        }

        // H) O = PW @ Tv^T ; I) /rowsum + cv, write
#pragma unroll
        for (int ct = 0; ct < 2; ++ct) {
            const bf16x8 pa = *(const bf16x8*)(QP + r16 * 40 + kg * 8);
            const bf16x8 vb = *(const bf16x8*)(buf + (ct * 16 + r16) * 32 + kg * 8);
            f32x4 ao = {0.f, 0.f, 0.f, 0.f};
            ao = __builtin_amdgcn_mfma_f32_16x16x32_bf16(pa, vb, ao, 0, 0, 0);
#pragma unroll
            for (int rg = 0; rg < 4; ++rg) {
                const int q = kg * 4 + rg;
                const int ch = h * 32 + ct * 16 + r16;
                const float val = ao[rg] / rowsumv[rg] + ckv[256 + ch];
                O[(size_t)(s * 16 + q) * 256 + ch] = f2b(val);
            }
        }
    }
}

// ---------------------------------------------------------------------------
extern "C" void kernel_launch(void* const* d_in, const int* in_sizes, int n_in,
                              void* d_out, int out_size, void* d_ws, size_t ws_size,
                              hipStream_t stream)
{
    const float* img          = (const float*)d_in[0];
    const float* kps          = (const float*)d_in[1];
    const unsigned char* vmsk = (const unsigned char*)d_in[2];
    const float* proj_w       = (const float*)d_in[3];
    const float* proj_b       = (const float*)d_in[4];
    const float* query_embed  = (const float*)d_in[5];
    const float* self_qkv_w   = (const float*)d_in[6];
    const float* self_qkv_b   = (const float*)d_in[7];
    const float* self_out_w   = (const float*)d_in[8];
    const float* self_out_b   = (const float*)d_in[9];
    const float* cross_qkv_w  = (const float*)d_in[10];
    const float* cross_qkv_b  = (const float*)d_in[11];
    const float* cross_out_w  = (const float*)d_in[12];
    const float* cross_out_b  = (const float*)d_in[13];
    const float* ffn1_w       = (const float*)d_in[14];
    const float* ffn1_b       = (const float*)d_in[15];
    const float* ffn2_w       = (const float*)d_in[16];
    const float* ffn2_b       = (const float*)d_in[17];
    const float* ln1_w        = (const float*)d_in[18];
    const float* ln1_b        = (const float*)d_in[19];
    const float* ln2_w        = (const float*)d_in[20];
    const float* ln2_b        = (const float*)d_in[21];
    const float* ln3_w        = (const float*)d_in[22];
    const float* ln3_b        = (const float*)d_in[23];
    const float* out_w        = (const float*)d_in[24];
    const float* out_b        = (const float*)d_in[25];
    float* out = (float*)d_out;

    // ---- workspace layout (~80 MB) ----
    char* W8 = (char*)d_ws;
    size_t off = 0;
    auto alloc = [&](size_t bytes) { void* p = W8 + off; off += (bytes + 255) & ~(size_t)255; return p; };
    float* tgt   = (float*)alloc(2097152 * 4);
    u16* Sb16    = (u16*)alloc(6291456 * 2);     // self-QKV bf16 [8192][768]
    float* ckv   = (float*)alloc(3 * 512 * 4);
    u16* imgTb   = (u16*)alloc(2097152 * 2);
    u16* KVb3    = (u16*)alloc(12582912 * 2);    // [8192][1536] all 3 layers K|V
    u16* tgtb    = (u16*)alloc(2097152 * 2);
    u16* Abuf    = (u16*)alloc(2097152 * 2);
    u16* Hbuf    = (u16*)alloc(8388608 * 2);
    u16* wAll    = (u16*)alloc(3670016 * 2);
    u16* WcombB  = (u16*)alloc(393216 * 2);      // (wCKV3 @ proj) weights
    int* valid   = (int*)alloc(512 * 4);

    u16* wProj  = wAll;             // 65536 (layout keeper)
    u16* wSQKV  = wProj + 65536;    // 3*768*256
    u16* wSOut  = wSQKV + 589824;   // 3*256*256
    u16* wCQKV  = wSOut + 196608;   // 3*768*256 (rows 0-255 of each layer = Wq)
    u16* wCOut  = wCQKV + 589824;   // 3*256*256
    u16* wF1    = wCOut + 196608;   // 3*1024*256
    u16* wF2    = wF1 + 786432;     // 3*256*1024
    u16* wCKV3  = wF2 + 786432;     // 3*512*256 cross K|V weights
    u16* wProjT = wCKV3 + 393216;   // 256*256 proj^T

    k_wconv<<<14340, 256, 0, stream>>>(proj_w, self_qkv_w, self_out_w, cross_qkv_w,
                                       cross_out_w, ffn1_w, ffn2_w, wAll,
                                       vmsk, valid, proj_b, cross_qkv_b, ckv);
    k_transpose<<<dim3(64, 4, 2), 256, 0, stream>>>(img, imgTb);
    gemm_mfma<64><<<dim3(2, 24), 256, 0, stream>>>(wCKV3, wProjT, nullptr,
                                                   nullptr, WcombB, 1536, 256, 256, 0);
    gemm_mfma<64><<<dim3(12, 128), 256, 0, stream>>>(imgTb, WcombB, nullptr,
                                                     nullptr, KVb3, 8192, 1536, 256, 0);
    k_init_tgt<<<8192, 256, 0, stream>>>(tgt, tgtb, query_embed);

    for (int l = 0; l < 3; ++l) {
        const int last = (l == 2);
        // ---- self attention (GEMM projection; v2 attention) ----
        gemm_mfma<64><<<dim3(6, 128), 256, 0, stream>>>(tgtb, wSQKV + (size_t)l * 196608,
            self_qkv_b + (size_t)l * 768, nullptr, Sb16, 8192, 768, 256, 0);
        k_self_attn<<<1024, 256, 0, stream>>>(Sb16, Abuf);
        gemm_ln<<<256, 256, 0, stream>>>(Abuf, wSOut + (size_t)l * 65536,
            self_out_b + (size_t)l * 256, tgt, tgtb,
            ln1_w + (size_t)l * 256, ln1_b + (size_t)l * 256, 256,
            nullptr, nullptr, nullptr);

        // ---- cross attention (one block per keypoint, 2 heads per wave) ----
        k_cross_attn<<<512, 256, 0, stream>>>(tgtb, wCQKV + (size_t)l * 196608,
                                              KVb3 + (size_t)l * 512, 1536,
                                              ckv + (size_t)l * 512, valid, kps, Abuf);
        gemm_ln<<<256, 256, 0, stream>>>(Abuf, wCOut + (size_t)l * 65536,
            cross_out_b + (size_t)l * 256, tgt, tgtb,
            ln2_w + (size_t)l * 256, ln2_b + (size_t)l * 256, 256,
            nullptr, nullptr, nullptr);

        // ---- FFN (final layer fuses the output head) ----
        gemm_mfma<64><<<dim3(8, 128), 256, 0, stream>>>(tgtb, wF1 + (size_t)l * 262144,
            ffn1_b + (size_t)l * 1024, nullptr, Hbuf, 8192, 1024, 256, 1);
        gemm_ln<<<256, 256, 0, stream>>>(Hbuf, wF2 + (size_t)l * 262144,
            ffn2_b + (size_t)l * 256, tgt, tgtb,
            ln3_w + (size_t)l * 256, ln3_b + (size_t)l * 256, 1024,
            last ? out_w : nullptr, last ? out_b : nullptr, last ? out : nullptr);
    }
}

// Round 22
// 351.890 us; speedup vs baseline: 1.1556x; 1.0052x over previous
//
#include <hip/hip_runtime.h>
#include <hip/hip_fp16.h>

#define LB __launch_bounds__(256)

typedef unsigned short u16;
typedef unsigned int   u32;
typedef __attribute__((ext_vector_type(8))) short bf16x8;   // 8 bf16 (4 VGPRs)
typedef __attribute__((ext_vector_type(4))) float f32x4;
typedef __attribute__((ext_vector_type(8))) u16  u16x8;

__device__ __forceinline__ u16 f2b(float f) {
    u32 u = __float_as_uint(f);
    u32 r = (u + 0x7fffu + ((u >> 16) & 1u)) >> 16;
    return (u16)r;
}
__device__ __forceinline__ float b2f(u16 h) {
    return __uint_as_float((u32)h << 16);
}

#define QSCALE 0.17677669529663687f

// ---------------------------------------------------------------------------
// B=2 N=256 C=256 HF=WF=64 ROI=15(225) HID=256 HEADS=8 Dh=32 DEPTH=3 FFN=1024
// NQ=16 -> seqs S=512, MT=8192.
// r22: self-attn -> v4 (grid 512, two head-chains per wave, r21-verified
// pattern); cross-attn hoists tgt A-fragments out of the head loop;
// k_transpose merged into k_wconv tail blocks (one fewer dispatch).
// ---------------------------------------------------------------------------

// ---------- weights fp32->bf16 + repack + prep + image transpose -----------
__global__ LB void k_wconv(const float* __restrict__ s0, const float* __restrict__ s1,
                           const float* __restrict__ s2, const float* __restrict__ s3,
                           const float* __restrict__ s4, const float* __restrict__ s5,
                           const float* __restrict__ s6, u16* __restrict__ dst,
                           const unsigned char* __restrict__ m, int* __restrict__ valid,
                           const float* __restrict__ pb,
                           const float* __restrict__ cqkv_b,
                           float* __restrict__ ckv,
                           const float* __restrict__ img, u16* __restrict__ imgTb)
{
    __shared__ float tile[64][65];
    if (blockIdx.x >= 14336) {
        const int pblk = blockIdx.x - 14336;
        if (pblk == 0) {
            __shared__ int flag;
            if (threadIdx.x == 0) flag = 0;
            __syncthreads();
            int loc = 0;
            for (int off = threadIdx.x; off < 512; off += 256)
                if ((off & 3) != 0 && m[off] != 0) loc = 1;
            if (loc) atomicOr(&flag, 1);
            __syncthreads();
            const bool bytelay = (flag != 0);
            for (int s = threadIdx.x; s < 512; s += 256)
                valid[s] = bytelay ? (int)(m[s] != 0) : (int)(((const int*)m)[s] != 0);
        } else if (pblk < 4) {
            const int l = pblk - 1;   // 0..2
            const float* Wv = s3 + (size_t)l * 196608 + 131072;
            const float* vb = cqkv_b + (size_t)l * 768 + 512;
            const int o = threadIdx.x;
            float c = 0.f;
            for (int cc = 0; cc < 256; cc += 4) {
                const float4 p4 = *(const float4*)(pb + cc);
                const float4 v4 = *(const float4*)(Wv + (size_t)o * 256 + cc);
                c += p4.x * v4.x + p4.y * v4.y + p4.z * v4.z + p4.w * v4.w;
            }
            ckv[l * 512 + o]       = cqkv_b[(size_t)l * 768 + o];  // bq (fused Q-proj)
            ckv[l * 512 + 256 + o] = c + vb[o];                    // cv (epilogue)
        } else {
            // image transpose: pblk-4 in [0,512) decodes old dim3(64,4,2)
            const int idx = pblk - 4;
            const int b  = idx >> 8;
            const int rem = idx & 255;
            const int c0 = (rem >> 6) * 64;
            const int p0 = (rem & 63) * 64;
            const int t  = threadIdx.x;
            const int tr = t >> 6, tc = t & 63;
#pragma unroll
            for (int p = 0; p < 16; ++p) {
                const int i = p * 4 + tr;
                tile[i][tc] = img[((size_t)(b * 256 + c0 + i)) * 4096 + p0 + tc];
            }
            __syncthreads();
#pragma unroll
            for (int p = 0; p < 16; ++p) {
                const int jj = p * 4 + tr;
                imgTb[((size_t)(b * 4096 + p0 + jj)) * 256 + c0 + tc] = f2b(tile[tc][jj]);
            }
        }
        return;
    }
    const int e = blockIdx.x * 256 + threadIdx.x;
    if (e >= 3670016) return;
    float v;
    int i = e;
    if (i < 65536) v = s0[i];
    else if ((i -= 65536) < 589824) v = s1[i];
    else if ((i -= 589824) < 196608) v = s2[i];
    else if ((i -= 196608) < 589824) v = s3[i];
    else if ((i -= 589824) < 196608) v = s4[i];
    else if ((i -= 196608) < 786432) v = s5[i];
    else if ((i -= 786432) < 786432) v = s6[i];
    else if ((i -= 786432) < 393216) {  // wCKV3: [l][512 rows (Wk|Wv)][256]
        const int l = i / 131072;
        const int r = (i - l * 131072) >> 8;
        const int c = i & 255;
        v = s3[(size_t)l * 196608 + (size_t)(256 + r) * 256 + c];
    } else {                            // projT: [c][o] = proj_w[o][c]
        i -= 393216;
        v = s0[(i & 255) * 256 + (i >> 8)];
    }
    dst[e] = f2b(v);
}

// ---------- bf16 MFMA GEMM: C[M,N] = A[M,K](bf16) @ W[N,K](bf16)^T + bias --
template<int BM>
__global__ LB void gemm_mfma(const u16* __restrict__ A, const u16* __restrict__ W,
                             const float* __restrict__ bias,
                             float* __restrict__ Cf, u16* __restrict__ Cb,
                             int M, int N, int K, int relu)
{
    constexpr int BN = 128;
    __shared__ u16 lds[2][(BM + BN) * 64];
    const int t = threadIdx.x;
    const int wid = t >> 6, lane = t & 63;
    const int bm = blockIdx.y * BM, bn = blockIdx.x * BN;
    const int KT = K >> 6;

    auto stage = [&](int buf, int kt) {
        const int k0 = kt * 64;
        const int rr = t >> 3;
        const int u  = t & 7;
#pragma unroll
        for (int q = 0; q < BM / 32; ++q) {
            const int r = q * 32 + rr;
            const u16* src = A + (size_t)(bm + r) * K + k0 + ((u ^ (r & 7)) << 3);
            __builtin_amdgcn_global_load_lds(
                (const __attribute__((address_space(1))) void*)src,
                (__attribute__((address_space(3))) void*)&lds[buf][q * 2048 + wid * 512],
                16, 0, 0);
        }
#pragma unroll
        for (int q = 0; q < 4; ++q) {
            const int r = q * 32 + rr;
            const u16* src = W + (size_t)(bn + r) * K + k0 + ((u ^ (r & 7)) << 3);
            __builtin_amdgcn_global_load_lds(
                (const __attribute__((address_space(1))) void*)src,
                (__attribute__((address_space(3))) void*)&lds[buf][BM * 64 + q * 2048 + wid * 512],
                16, 0, 0);
        }
    };

    const int wr = wid >> 1, wc = wid & 1;
    constexpr int MR = BM / 32;
    f32x4 acc[MR][4];
    const f32x4 z = {0.f, 0.f, 0.f, 0.f};
#pragma unroll
    for (int mi = 0; mi < MR; ++mi)
#pragma unroll
        for (int ni = 0; ni < 4; ++ni) acc[mi][ni] = z;

    const int r16 = lane & 15, kg = lane >> 4;

    stage(0, 0);
    int cur = 0;
    for (int kt = 0; kt < KT; ++kt) {
        asm volatile("s_waitcnt vmcnt(0)" ::: "memory");
        __syncthreads();
        if (kt + 1 < KT) stage(cur ^ 1, kt + 1);
        const u16* pA = lds[cur];
        const u16* pB = lds[cur] + BM * 64;
#pragma unroll
        for (int kk = 0; kk < 2; ++kk) {
            const int s = kk * 4 + kg;
            bf16x8 afr[MR], bfr[4];
#pragma unroll
            for (int mi = 0; mi < MR; ++mi) {
                const int r = wr * (BM / 2) + mi * 16 + r16;
                afr[mi] = *(const bf16x8*)(pA + r * 64 + ((s ^ (r & 7)) << 3));
            }
#pragma unroll
            for (int ni = 0; ni < 4; ++ni) {
                const int c = wc * 64 + ni * 16 + r16;
                bfr[ni] = *(const bf16x8*)(pB + c * 64 + ((s ^ (c & 7)) << 3));
            }
#pragma unroll
            for (int mi = 0; mi < MR; ++mi)
#pragma unroll
                for (int ni = 0; ni < 4; ++ni)
                    acc[mi][ni] = __builtin_amdgcn_mfma_f32_16x16x32_bf16(
                        afr[mi], bfr[ni], acc[mi][ni], 0, 0, 0);
        }
        cur ^= 1;
    }

#pragma unroll
    for (int mi = 0; mi < MR; ++mi) {
#pragma unroll
        for (int ni = 0; ni < 4; ++ni) {
            const int col = bn + wc * 64 + ni * 16 + r16;
            const float bs = bias ? bias[col] : 0.0f;
#pragma unroll
            for (int rg = 0; rg < 4; ++rg) {
                const int row = bm + wr * (BM / 2) + mi * 16 + kg * 4 + rg;
                float v = acc[mi][ni][rg] + bs;
                if (relu) v = fmaxf(v, 0.0f);
                if (Cf) Cf[(size_t)row * N + col] = v;
                if (Cb) Cb[(size_t)row * N + col] = f2b(v);
            }
        }
    }
}

// ---------- fused GEMM + residual + LayerNorm (+ optional output head) -----
__global__ LB void gemm_ln(const u16* __restrict__ A, const u16* __restrict__ W,
                           const float* __restrict__ bias,
                           float* __restrict__ tgt, u16* __restrict__ tgtb,
                           const float* __restrict__ lnw, const float* __restrict__ lnb,
                           int K,
                           const float* __restrict__ ow, const float* __restrict__ ob,
                           float* __restrict__ outp)
{
    __shared__ u16 lA[32 * 64];
    __shared__ u16 lB[256 * 64];
    __shared__ float psum[2][32];
    __shared__ float psq[2][32];
    __shared__ float hsum[2][32][4];
    const int t = threadIdx.x;
    const int wid = t >> 6, lane = t & 63;
    const int r16 = lane & 15, kg = lane >> 4;
    const int wr = wid >> 1, wc = wid & 1;
    const int bm = blockIdx.x * 32;
    const int KT = K >> 6;

    f32x4 acc[8];
    const f32x4 z = {0.f, 0.f, 0.f, 0.f};
#pragma unroll
    for (int ni = 0; ni < 8; ++ni) acc[ni] = z;

    for (int kt = 0; kt < KT; ++kt) {
        const int k0 = kt * 64;
        const int rr = t >> 3;
        const int u  = t & 7;
        {
            const int r = rr;
            const u16* src = A + (size_t)(bm + r) * K + k0 + ((u ^ (r & 7)) << 3);
            __builtin_amdgcn_global_load_lds(
                (const __attribute__((address_space(1))) void*)src,
                (__attribute__((address_space(3))) void*)&lA[wid * 512],
                16, 0, 0);
        }
#pragma unroll
        for (int q = 0; q < 8; ++q) {
            const int r = q * 32 + rr;
            const u16* src = W + (size_t)r * K + k0 + ((u ^ (r & 7)) << 3);
            __builtin_amdgcn_global_load_lds(
                (const __attribute__((address_space(1))) void*)src,
                (__attribute__((address_space(3))) void*)&lB[q * 2048 + wid * 512],
                16, 0, 0);
        }
        asm volatile("s_waitcnt vmcnt(0)" ::: "memory");
        __syncthreads();
#pragma unroll
        for (int kk = 0; kk < 2; ++kk) {
            const int s = kk * 4 + kg;
            const int ra = wr * 16 + r16;
            const bf16x8 afr = *(const bf16x8*)(lA + ra * 64 + ((s ^ (ra & 7)) << 3));
#pragma unroll
            for (int ni = 0; ni < 8; ++ni) {
                const int c = wc * 128 + ni * 16 + r16;
                const bf16x8 bfr = *(const bf16x8*)(lB + c * 64 + ((s ^ (c & 7)) << 3));
                acc[ni] = __builtin_amdgcn_mfma_f32_16x16x32_bf16(afr, bfr, acc[ni], 0, 0, 0);
            }
        }
        __syncthreads();
    }

    float xv[4][8];
    float bcol[8], wcol[8], bncol[8];
#pragma unroll
    for (int ni = 0; ni < 8; ++ni) {
        const int c = wc * 128 + ni * 16 + r16;
        bcol[ni]  = bias[c];
        wcol[ni]  = lnw[c];
        bncol[ni] = lnb[c];
    }
#pragma unroll
    for (int rg = 0; rg < 4; ++rg) {
        const int row = bm + wr * 16 + kg * 4 + rg;
#pragma unroll
        for (int ni = 0; ni < 8; ++ni) {
            const int c = wc * 128 + ni * 16 + r16;
            xv[rg][ni] = tgt[(size_t)row * 256 + c] + acc[ni][rg] + bcol[ni];
        }
    }
#pragma unroll
    for (int rg = 0; rg < 4; ++rg) {
        float s = 0.f;
#pragma unroll
        for (int ni = 0; ni < 8; ++ni) s += xv[rg][ni];
#pragma unroll
        for (int m = 1; m < 16; m <<= 1) s += __shfl_xor(s, m);
        if (r16 == 0) psum[wc][wr * 16 + kg * 4 + rg] = s;
    }
    __syncthreads();
    float mu[4];
#pragma unroll
    for (int rg = 0; rg < 4; ++rg) {
        const int rl = wr * 16 + kg * 4 + rg;
        mu[rg] = (psum[0][rl] + psum[1][rl]) * (1.0f / 256.0f);
    }
#pragma unroll
    for (int rg = 0; rg < 4; ++rg) {
        float q = 0.f;
#pragma unroll
        for (int ni = 0; ni < 8; ++ni) {
            const float d = xv[rg][ni] - mu[rg];
            q += d * d;
        }
#pragma unroll
        for (int m = 1; m < 16; m <<= 1) q += __shfl_xor(q, m);
        if (r16 == 0) psq[wc][wr * 16 + kg * 4 + rg] = q;
    }
    __syncthreads();
    float onorm[4][8];
#pragma unroll
    for (int rg = 0; rg < 4; ++rg) {
        const int rl = wr * 16 + kg * 4 + rg;
        const int row = bm + rl;
        const float var = (psq[0][rl] + psq[1][rl]) * (1.0f / 256.0f);
        const float inv = 1.0f / sqrtf(var + 1e-5f);
#pragma unroll
        for (int ni = 0; ni < 8; ++ni) {
            const int c = wc * 128 + ni * 16 + r16;
            const float o = (xv[rg][ni] - mu[rg]) * inv * wcol[ni] + bncol[ni];
            onorm[rg][ni] = o;
            tgt[(size_t)row * 256 + c]  = o;
            tgtb[(size_t)row * 256 + c] = f2b(o);
        }
    }

    if (outp) {
#pragma unroll
        for (int j = 0; j < 4; ++j) {
            float wj[8];
#pragma unroll
            for (int ni = 0; ni < 8; ++ni)
                wj[ni] = ow[j * 256 + wc * 128 + ni * 16 + r16];
#pragma unroll
            for (int rg = 0; rg < 4; ++rg) {
                float p = 0.f;
#pragma unroll
                for (int ni = 0; ni < 8; ++ni) p += onorm[rg][ni] * wj[ni];
#pragma unroll
                for (int m = 1; m < 16; m <<= 1) p += __shfl_xor(p, m);
                if (r16 == 0) hsum[wc][wr * 16 + kg * 4 + rg][j] = p;
            }
        }
        __syncthreads();
        if (t < 128) {
            const int row = t >> 2, j = t & 3;
            outp[(size_t)(bm + row) * 4 + j] =
                hsum[0][row][j] + hsum[1][row][j] + ob[j];
        }
    }
}

// ---------- init tgt (fp32 + bf16) -----------------------------------------
__global__ LB void k_init_tgt(float* __restrict__ tgt, u16* __restrict__ tgtb,
                              const float* __restrict__ qe)
{
    const int e = blockIdx.x * 256 + threadIdx.x;
    const int c = e & 255;
    const int row = e >> 8;
    const int i = row & 15;
    const float v = qe[(i << 8) | c];
    tgt[e] = v;
    tgtb[e] = f2b(v);
}

// ---------- self attention v4: one block per seq, 2 heads per wave ---------
// grid 512. QKV bf16 [8192][768].
__global__ LB void k_self_attn(const u16* __restrict__ QKV, u16* __restrict__ O)
{
    __shared__ __align__(16) u16 arena[4][1536];   // per wave: p_lds[16][32] | vT[32][32]
    const int t = threadIdx.x;
    const int lane = t & 63, wid = t >> 6;
    const int r16 = lane & 15, kg = lane >> 4;
    const int s = blockIdx.x;

    u16* p_lds = &arena[wid][0];
    u16* vT    = &arena[wid][512];

    for (int hh = 0; hh < 2; ++hh) {
        const int h = hh * 4 + wid;

        const bf16x8 qfr = *(const bf16x8*)(QKV + (size_t)(s * 16 + r16) * 768 + h * 32 + kg * 8);
        const bf16x8 kfr = *(const bf16x8*)(QKV + (size_t)(s * 16 + r16) * 768 + 256 + h * 32 + kg * 8);
        f32x4 sv = {0.f, 0.f, 0.f, 0.f};
        sv = __builtin_amdgcn_mfma_f32_16x16x32_bf16(qfr, kfr, sv, 0, 0, 0);

        float ev[4], rowsum[4];
#pragma unroll
        for (int rg = 0; rg < 4; ++rg) ev[rg] = sv[rg] * QSCALE;
#pragma unroll
        for (int rg = 0; rg < 4; ++rg) {
            float mx = ev[rg];
#pragma unroll
            for (int m = 1; m < 16; m <<= 1) mx = fmaxf(mx, __shfl_xor(mx, m));
            ev[rg] = __expf(ev[rg] - mx);
            float ps = ev[rg];
#pragma unroll
            for (int m = 1; m < 16; m <<= 1) ps += __shfl_xor(ps, m);
            rowsum[rg] = ps;
        }

#pragma unroll
        for (int rg = 0; rg < 4; ++rg)
            p_lds[(kg * 4 + rg) * 32 + r16] = f2b(ev[rg]);
        {
            const int zq = lane & 15, zc = 16 + (lane >> 4) * 4;
#pragma unroll
            for (int j = 0; j < 4; ++j) p_lds[zq * 32 + zc + j] = 0;
        }
        {
            const int key = lane >> 2, ch8 = (lane & 3) * 8;
            const u16x8 v = *(const u16x8*)(QKV + (size_t)(s * 16 + key) * 768 + 512 + h * 32 + ch8);
#pragma unroll
            for (int j = 0; j < 8; ++j)
                vT[(ch8 + j) * 32 + key] = ((const u16*)&v)[j];
            const int zc0 = lane >> 1, zk0 = 16 + (lane & 1) * 8;
#pragma unroll
            for (int j = 0; j < 8; ++j) vT[zc0 * 32 + zk0 + j] = 0;
        }

#pragma unroll
        for (int ct = 0; ct < 2; ++ct) {
            const bf16x8 pa = *(const bf16x8*)(p_lds + r16 * 32 + kg * 8);
            const bf16x8 vb = *(const bf16x8*)(vT + (ct * 16 + r16) * 32 + kg * 8);
            f32x4 ao = {0.f, 0.f, 0.f, 0.f};
            ao = __builtin_amdgcn_mfma_f32_16x16x32_bf16(pa, vb, ao, 0, 0, 0);
#pragma unroll
            for (int rg = 0; rg < 4; ++rg) {
                const int q = kg * 4 + rg;
                O[(size_t)(s * 16 + q) * 256 + h * 32 + ct * 16 + r16] = f2b(ao[rg] / rowsum[rg]);
            }
        }
    }
}

// ---------- cross attention v4.1: block per keypoint, 2 heads/wave, ta hoist
__global__ LB void k_cross_attn(const u16* __restrict__ tgtb,
                                const u16* __restrict__ wQ,
                                const u16* __restrict__ KV, int kvs,
                                const float* __restrict__ ckv,
                                const int* __restrict__ valid,
                                const float* __restrict__ kps,
                                u16* __restrict__ O)
{
    __shared__ __align__(16) char arena[64832];
    u16* Wm  = (u16*)arena;
    u16* WmT = (u16*)(arena + 14400);

    const int t = threadIdx.x;
    const int lane = t & 63, wid = t >> 6;
    const int r16 = lane & 15, kg = lane >> 4;
    const int s = blockIdx.x;              // one block per keypoint
    const int b = s >> 8, n = s & 255;

    u16* buf = (u16*)(arena + 22848 + wid * 10496);           // [32][32]
    u16* p_b = (u16*)(arena + 22848 + wid * 10496 + 2048);    // [16][264]
    u16* QP  = p_b;                                            // [16][40] overlay

    for (int e = t; e < 16208; e += 256) ((u32*)arena)[e] = 0;
    __syncthreads();

    const float kpy = kps[(b * 256 + n) * 2 + 0];
    const float kpx = kps[(b * 256 + n) * 2 + 1];
    const float gx0 = rintf(kpx) - 7.0f;
    const float gy0 = rintf(kpy) - 7.0f;
    const float gxn0 = gx0 / 511.0f * 2.0f - 1.0f;
    const float gyn0 = gy0 / 511.0f * 2.0f - 1.0f;
    const float xb = ((gxn0 + 1.f) * 64.f - 1.f) * 0.5f;
    const float yb = ((gyn0 + 1.f) * 64.f - 1.f) * 0.5f;
    const int x0b = (int)floorf(xb);
    const int y0b = (int)floorf(yb);

    // ---- W build once per keypoint ----
    if (t < 225) {
        const int iy = t / 15, ix = t - iy * 15;
        const float gy = rintf(kpy) + (float)(iy - 7);
        const float gx = rintf(kpx) + (float)(ix - 7);
        const float gxn = gx / 511.0f * 2.0f - 1.0f;
        const float gyn = gy / 511.0f * 2.0f - 1.0f;
        const bool inval = (gxn < -1.f) || (gyn < -1.f) || (gxn > 1.f) || (gyn > 1.f);
        const float x = ((gxn + 1.f) * 64.f - 1.f) * 0.5f;
        const float y = ((gyn + 1.f) * 64.f - 1.f) * 0.5f;
        const float x0f = floorf(x), y0f = floorf(y);
        const float wx = x - x0f, wy = y - y0f;
        const int x0 = (int)x0f, y0 = (int)y0f;
#pragma unroll
        for (int tt = 0; tt < 4; ++tt) {
            const int dy = tt >> 1, dx = tt & 1;
            const int yi = y0 + dy, xi = x0 + dx;
            const bool ok = (yi >= 0) && (yi < 64) && (xi >= 0) && (xi < 64) && !inval;
            const float w = (dy ? wy : 1.f - wy) * (dx ? wx : 1.f - wx);
            if (ok) {
                const int cell = (yi - y0b) * 4 + (xi - x0b);
                const u16 wb = f2b(w);
                Wm[t * 32 + ((((cell >> 3) ^ (t & 3)) << 3) | (cell & 7))] = wb;
                WmT[cell * 264 + t] = wb;
            }
        }
    }

    const int cell = lane >> 2, ch8 = (lane & 3) * 8;
    const int cy = cell >> 2, cx = cell & 3;
    const int py = min(max(y0b + cy, 0), 63);
    const int px = min(max(x0b + cx, 0), 63);
    const bool vld = valid[s] != 0;

    // hoist tgt A-fragments (shared by both heads' Q-proj)
    bf16x8 ta[8];
#pragma unroll
    for (int ks = 0; ks < 8; ++ks)
        ta[ks] = *(const bf16x8*)(tgtb + (size_t)(s * 16 + r16) * 256 + ks * 32 + kg * 8);

    // ---- two heads per wave: h = wid (hh=0), wid+4 (hh=1) ----
    for (int hh = 0; hh < 2; ++hh) {
        const int h = hh * 4 + wid;
        const size_t texidx = (size_t)(b * 4096 + py * 64 + px) * kvs + h * 32 + ch8;

        // fused Q-proj: Q'[16 q][32 ch] = tgt @ wQ_h^T + bq  (16 MFMA)
#pragma unroll
        for (int ct = 0; ct < 2; ++ct) {
            f32x4 aq = {0.f, 0.f, 0.f, 0.f};
#pragma unroll
            for (int ks = 0; ks < 8; ++ks) {
                const bf16x8 wb = *(const bf16x8*)(wQ + (size_t)(h * 32 + ct * 16 + r16) * 256 + ks * 32 + kg * 8);
                aq = __builtin_amdgcn_mfma_f32_16x16x32_bf16(ta[ks], wb, aq, 0, 0, 0);
            }
            const float bq = ckv[h * 32 + ct * 16 + r16];
#pragma unroll
            for (int rg = 0; rg < 4; ++rg)
                QP[(kg * 4 + rg) * 40 + ct * 16 + r16] = f2b(aq[rg] + bq);
        }
        // Tk load (wave-local; rows 0-15 x all 32 cols)
        *(u16x8*)(buf + cell * 32 + ch8) = *(const u16x8*)(KV + texidx);

        if (hh == 0) __syncthreads();   // Wm/WmT visible before first S

        // A) QT = Q' @ Tk (1 MFMA)
        {
            const bf16x8 qfr = *(const bf16x8*)(QP + r16 * 40 + kg * 8);
            const bf16x8 tfr = *(const bf16x8*)(buf + r16 * 32 + kg * 8);
            f32x4 aq = {0.f, 0.f, 0.f, 0.f};
            aq = __builtin_amdgcn_mfma_f32_16x16x32_bf16(qfr, tfr, aq, 0, 0, 0);
#pragma unroll
            for (int rg = 0; rg < 4; ++rg)
                QP[(kg * 4 + rg) * 40 + r16] = f2b(aq[rg]);
        }

        // B) S = QT @ Wm^T ; C) in-register softmax
        float ev[4][15];
        {
            const bf16x8 afr = *(const bf16x8*)(QP + r16 * 40 + kg * 8);
#pragma unroll
            for (int tile = 0; tile < 15; ++tile) {
                const int p = tile * 16 + r16;
                const int rc = p < 225 ? p : 224;
                const bf16x8 bfr = *(const bf16x8*)(Wm + rc * 32 + ((kg ^ (rc & 3)) << 3));
                f32x4 acc = {0.f, 0.f, 0.f, 0.f};
                acc = __builtin_amdgcn_mfma_f32_16x16x32_bf16(afr, bfr, acc, 0, 0, 0);
#pragma unroll
                for (int rg = 0; rg < 4; ++rg) {
                    float sv = acc[rg] * QSCALE;
                    if (p > 224) sv = -1e30f;
                    if (!vld && p > 0) sv = -1e30f;
                    ev[rg][tile] = sv;
                }
            }
        }
        float rowsumv[4];
#pragma unroll
        for (int rg = 0; rg < 4; ++rg) {
            float mx = -1e30f;
#pragma unroll
            for (int k = 0; k < 15; ++k) mx = fmaxf(mx, ev[rg][k]);
#pragma unroll
            for (int m = 1; m < 16; m <<= 1) mx = fmaxf(mx, __shfl_xor(mx, m));
            float ps = 0.f;
#pragma unroll
            for (int k = 0; k < 15; ++k) {
                ev[rg][k] = __expf(ev[rg][k] - mx);
                ps += ev[rg][k];
            }
#pragma unroll
            for (int m = 1; m < 16; m <<= 1) ps += __shfl_xor(ps, m);
            rowsumv[rg] = ps;
        }

        // D) P -> p_b; re-zero pad cols 225-255
#pragma unroll
        for (int rg = 0; rg < 4; ++rg)
#pragma unroll
            for (int k = 0; k < 15; ++k) {
                const int p = k * 16 + r16;
                if (p < 225) p_b[(kg * 4 + rg) * 264 + p] = f2b(ev[rg][k]);
            }
        for (int e = lane; e < 496; e += 64) {
            const int row = e / 31;
            p_b[row * 264 + 225 + (e - row * 31)] = 0;
        }

        // E) TvT into buf (overwrite Tk; zero leftover cols rows 0-15)
        {
            const u16x8 v = *(const u16x8*)(KV + texidx + 256);
#pragma unroll
            for (int j = 0; j < 8; ++j)
                buf[(ch8 + j) * 32 + cell] = ((const u16*)&v)[j];
            const int zr = lane & 15, zc0 = 16 + (lane >> 4) * 4;
#pragma unroll
            for (int j = 0; j < 4; ++j) buf[zr * 32 + zc0 + j] = 0;
        }

        // F) PW = P @ W (8-chain)
        f32x4 pw = {0.f, 0.f, 0.f, 0.f};
#pragma unroll
        for (int ks = 0; ks < 8; ++ks) {
            const bf16x8 pa = *(const bf16x8*)(p_b + r16 * 264 + ks * 32 + kg * 8);
            const bf16x8 wb = *(const bf16x8*)(WmT + r16 * 264 + ks * 32 + kg * 8);
            pw = __builtin_amdgcn_mfma_f32_16x16x32_bf16(pa, wb, pw, 0, 0, 0);
        }

        // G) PW -> QP; re-zero cols 16-31
#pragma unroll
        for (int rg = 0; rg < 4; ++rg)
            QP[(kg * 4 + rg) * 40 + r16] = f2b(pw[rg]);
        {
            const int zq = lane & 15, zc0 = 16 + (lane >> 4) * 4;
#pragma unroll
            for (int j = 0; j < 4; ++j) QP[zq * 40 + zc0 + j] = 0;
        }

        // H) O = PW @ Tv^T ; I) /rowsum + cv, write
#pragma unroll
        for (int ct = 0; ct < 2; ++ct) {
            const bf16x8 pa = *(const bf16x8*)(QP + r16 * 40 + kg * 8);
            const bf16x8 vb = *(const bf16x8*)(buf + (ct * 16 + r16) * 32 + kg * 8);
            f32x4 ao = {0.f, 0.f, 0.f, 0.f};
            ao = __builtin_amdgcn_mfma_f32_16x16x32_bf16(pa, vb, ao, 0, 0, 0);
#pragma unroll
            for (int rg = 0; rg < 4; ++rg) {
                const int q = kg * 4 + rg;
                const int ch = h * 32 + ct * 16 + r16;
                const float val = ao[rg] / rowsumv[rg] + ckv[256 + ch];
                O[(size_t)(s * 16 + q) * 256 + ch] = f2b(val);
            }
        }
    }
}

// ---------------------------------------------------------------------------
extern "C" void kernel_launch(void* const* d_in, const int* in_sizes, int n_in,
                              void* d_out, int out_size, void* d_ws, size_t ws_size,
                              hipStream_t stream)
{
    const float* img          = (const float*)d_in[0];
    const float* kps          = (const float*)d_in[1];
    const unsigned char* vmsk = (const unsigned char*)d_in[2];
    const float* proj_w       = (const float*)d_in[3];
    const float* proj_b       = (const float*)d_in[4];
    const float* query_embed  = (const float*)d_in[5];
    const float* self_qkv_w   = (const float*)d_in[6];
    const float* self_qkv_b   = (const float*)d_in[7];
    const float* self_out_w   = (const float*)d_in[8];
    const float* self_out_b   = (const float*)d_in[9];
    const float* cross_qkv_w  = (const float*)d_in[10];
    const float* cross_qkv_b  = (const float*)d_in[11];
    const float* cross_out_w  = (const float*)d_in[12];
    const float* cross_out_b  = (const float*)d_in[13];
    const float* ffn1_w       = (const float*)d_in[14];
    const float* ffn1_b       = (const float*)d_in[15];
    const float* ffn2_w       = (const float*)d_in[16];
    const float* ffn2_b       = (const float*)d_in[17];
    const float* ln1_w        = (const float*)d_in[18];
    const float* ln1_b        = (const float*)d_in[19];
    const float* ln2_w        = (const float*)d_in[20];
    const float* ln2_b        = (const float*)d_in[21];
    const float* ln3_w        = (const float*)d_in[22];
    const float* ln3_b        = (const float*)d_in[23];
    const float* out_w        = (const float*)d_in[24];
    const float* out_b        = (const float*)d_in[25];
    float* out = (float*)d_out;

    // ---- workspace layout (~80 MB) ----
    char* W8 = (char*)d_ws;
    size_t off = 0;
    auto alloc = [&](size_t bytes) { void* p = W8 + off; off += (bytes + 255) & ~(size_t)255; return p; };
    float* tgt   = (float*)alloc(2097152 * 4);
    u16* Sb16    = (u16*)alloc(6291456 * 2);     // self-QKV bf16 [8192][768]
    float* ckv   = (float*)alloc(3 * 512 * 4);
    u16* imgTb   = (u16*)alloc(2097152 * 2);
    u16* KVb3    = (u16*)alloc(12582912 * 2);    // [8192][1536] all 3 layers K|V
    u16* tgtb    = (u16*)alloc(2097152 * 2);
    u16* Abuf    = (u16*)alloc(2097152 * 2);
    u16* Hbuf    = (u16*)alloc(8388608 * 2);
    u16* wAll    = (u16*)alloc(3670016 * 2);
    u16* WcombB  = (u16*)alloc(393216 * 2);      // (wCKV3 @ proj) weights
    int* valid   = (int*)alloc(512 * 4);

    u16* wProj  = wAll;             // 65536 (layout keeper)
    u16* wSQKV  = wProj + 65536;    // 3*768*256
    u16* wSOut  = wSQKV + 589824;   // 3*256*256
    u16* wCQKV  = wSOut + 196608;   // 3*768*256 (rows 0-255 of each layer = Wq)
    u16* wCOut  = wCQKV + 589824;   // 3*256*256
    u16* wF1    = wCOut + 196608;   // 3*1024*256
    u16* wF2    = wF1 + 786432;     // 3*256*1024
    u16* wCKV3  = wF2 + 786432;     // 3*512*256 cross K|V weights
    u16* wProjT = wCKV3 + 393216;   // 256*256 proj^T

    // weights + prep + image transpose in one dispatch (14336 + 4 + 512 blocks)
    k_wconv<<<14852, 256, 0, stream>>>(proj_w, self_qkv_w, self_out_w, cross_qkv_w,
                                       cross_out_w, ffn1_w, ffn2_w, wAll,
                                       vmsk, valid, proj_b, cross_qkv_b, ckv,
                                       img, imgTb);
    gemm_mfma<64><<<dim3(2, 24), 256, 0, stream>>>(wCKV3, wProjT, nullptr,
                                                   nullptr, WcombB, 1536, 256, 256, 0);
    gemm_mfma<64><<<dim3(12, 128), 256, 0, stream>>>(imgTb, WcombB, nullptr,
                                                     nullptr, KVb3, 8192, 1536, 256, 0);
    k_init_tgt<<<8192, 256, 0, stream>>>(tgt, tgtb, query_embed);

    for (int l = 0; l < 3; ++l) {
        const int last = (l == 2);
        // ---- self attention (GEMM projection; v4 attention) ----
        gemm_mfma<64><<<dim3(6, 128), 256, 0, stream>>>(tgtb, wSQKV + (size_t)l * 196608,
            self_qkv_b + (size_t)l * 768, nullptr, Sb16, 8192, 768, 256, 0);
        k_self_attn<<<512, 256, 0, stream>>>(Sb16, Abuf);
        gemm_ln<<<256, 256, 0, stream>>>(Abuf, wSOut + (size_t)l * 65536,
            self_out_b + (size_t)l * 256, tgt, tgtb,
            ln1_w + (size_t)l * 256, ln1_b + (size_t)l * 256, 256,
            nullptr, nullptr, nullptr);

        // ---- cross attention (one block per keypoint, 2 heads per wave) ----
        k_cross_attn<<<512, 256, 0, stream>>>(tgtb, wCQKV + (size_t)l * 196608,
                                              KVb3 + (size_t)l * 512, 1536,
                                              ckv + (size_t)l * 512, valid, kps, Abuf);
        gemm_ln<<<256, 256, 0, stream>>>(Abuf, wCOut + (size_t)l * 65536,
            cross_out_b + (size_t)l * 256, tgt, tgtb,
            ln2_w + (size_t)l * 256, ln2_b + (size_t)l * 256, 256,
            nullptr, nullptr, nullptr);

        // ---- FFN (final layer fuses the output head) ----
        gemm_mfma<64><<<dim3(8, 128), 256, 0, stream>>>(tgtb, wF1 + (size_t)l * 262144,
            ffn1_b + (size_t)l * 1024, nullptr, Hbuf, 8192, 1024, 256, 1);
        gemm_ln<<<256, 256, 0, stream>>>(Hbuf, wF2 + (size_t)l * 262144,
            ffn2_b + (size_t)l * 256, tgt, tgtb,
            ln3_w + (size_t)l * 256, ln3_b + (size_t)l * 256, 1024,
            last ? out_w : nullptr, last ? out_b : nullptr, last ? out : nullptr);
    }
}